// Round 15
// baseline (355.752 us; speedup 1.0000x reference)
//
#include <hip/hip_runtime.h>

#define B_    64
#define C_    256
#define HW_   1024
#define NPIX  (B_ * HW_)
#define K_    1024
#define TAU_FLAG    2.0e-4f
#define CAND_MARGIN 2.2e-4f
#define MAXFLAG     8192
#define MAXCAND     65536

typedef unsigned short u16;
typedef unsigned int   u32;
typedef unsigned long long u64;
typedef __attribute__((ext_vector_type(8))) __bf16 bf16x8v;
typedef __attribute__((ext_vector_type(4))) float  float4v;
typedef __attribute__((address_space(1))) void gvoid;
typedef __attribute__((address_space(3))) void lvoid;

// Rounding barriers: force a separately-rounded f32 mul/add/sub (defeat
// -ffp-contract=fast fusion and any reassociation across the boundary).
__device__ __forceinline__ float fmul_x(float a, float b) { float p = a * b; asm volatile("" : "+v"(p)); return p; }
__device__ __forceinline__ float fadd_x(float a, float b) { float s = a + b; asm volatile("" : "+v"(s)); return s; }
__device__ __forceinline__ float fsub_x(float a, float b) { float s = a - b; asm volatile("" : "+v"(s)); return s; }

// f32 -> bf16 round-to-nearest-even (finite inputs only), and back.
__device__ __forceinline__ u16 bf16_rne(float f) {
    u32 u = __float_as_uint(f);
    u32 r = u + 0x7FFFu + ((u >> 16) & 1u);
    return (u16)(r >> 16);
}
__device__ __forceinline__ float bf16_to_f(u16 h) { return __uint_as_float(((u32)h) << 16); }

__device__ __forceinline__ uint4 pack8(const u16* h) {
    return make_uint4((u32)h[0] | ((u32)h[1] << 16), (u32)h[2] | ((u32)h[3] << 16),
                      (u32)h[4] | ((u32)h[5] << 16), (u32)h[6] | ((u32)h[7] << 16));
}

// ---------------------------------------------------------------------------
// numpy pairwise sum replica for 256 contiguous squares (unchanged).
// ---------------------------------------------------------------------------
__device__ __forceinline__ float np_sumsq_256(const float* __restrict__ a) {
    float half[2];
#pragma unroll
    for (int h = 0; h < 2; ++h) {
        const float* p = a + h * 128;
        float r[8];
#pragma unroll
        for (int j = 0; j < 8; ++j) r[j] = fmul_x(p[j], p[j]);
        for (int i = 8; i < 128; i += 8)
#pragma unroll
            for (int j = 0; j < 8; ++j) r[j] = fadd_x(r[j], fmul_x(p[i + j], p[i + j]));
        half[h] = fadd_x(fadd_x(fadd_x(r[0], r[1]), fadd_x(r[2], r[3])),
                         fadd_x(fadd_x(r[4], r[5]), fadd_x(r[6], r[7])));
    }
    return fadd_x(half[0], half[1]);
}

// ---------------------------------------------------------------------------
// numpy einsum f32 dot replica (unchanged).
// ---------------------------------------------------------------------------
__device__ float np_einsum_dot_256(const float* __restrict__ xr,
                                   const float* __restrict__ er) {
    float acc0 = 0.f, acc1 = 0.f, acc2 = 0.f, acc3 = 0.f;
    for (int blk = 0; blk < 256; blk += 16) {
#pragma unroll
        for (int sub = 3; sub >= 0; --sub) {
            const int base = blk + sub * 4;
            acc0 = fadd_x(acc0, fmul_x(xr[base + 0], er[base + 0]));
            acc1 = fadd_x(acc1, fmul_x(xr[base + 1], er[base + 1]));
            acc2 = fadd_x(acc2, fmul_x(xr[base + 2], er[base + 2]));
            acc3 = fadd_x(acc3, fmul_x(xr[base + 3], er[base + 3]));
        }
    }
    return fadd_x(fadd_x(acc0, acc2), fadd_x(acc1, acc3));
}

// ---------------------------------------------------------------------------
// prep_e: zero counters + e_sq (np-pairwise replica, per-row serial, same
// arithmetic as the old esq kernel) + emb -> hi/lo bf16 staged tiles (body
// verbatim from the old cvt_e kernel). Grid 32 x 256.
// ---------------------------------------------------------------------------
__global__ __launch_bounds__(256) void prep_e_kernel(const float* __restrict__ emb,
                                                     float* __restrict__ esq,
                                                     u16* __restrict__ et_hi,
                                                     u16* __restrict__ et_lo,
                                                     int* pcount, int* ccount) {
    const int tid = threadIdx.x;
    if (blockIdx.x == 0 && tid == 0) { *pcount = 0; *ccount = 0; }
    const int k  = (blockIdx.x << 5) + (tid & 31);
    const int cg = tid >> 5;
    const int kb = k >> 7;
    const int kr = k & 127;
#pragma unroll
    for (int ct = 0; ct < 4; ++ct) {
        const int c = (ct << 6) + (cg << 3);
        const float* src = emb + (size_t)k * C_ + c;
        u16 h[8], l[8];
#pragma unroll
        for (int i = 0; i < 8; ++i) {
            const float f = src[i];
            h[i] = bf16_rne(f);
            l[i] = bf16_rne(f - bf16_to_f(h[i]));
        }
        const size_t off = ((size_t)((kb << 2) + ct) << 13) + (cg << 10) + (kr << 3);
        *(uint4*)(et_hi + off) = pack8(h);
        *(uint4*)(et_lo + off) = pack8(l);
    }
    if (tid < 32) {
        const int row = (blockIdx.x << 5) + tid;
        esq[row] = np_sumsq_256(emb + (size_t)row * C_);
    }
}

// ---------------------------------------------------------------------------
// MFMA bf16x3 scoring + top-2 + flag + (optional) fused STE out-write.
// v8 = round-14 kernel (r8 schedule + fused cvt_x) + epilogue: when outp is
// non-null, each block gathers its 64 winners' emb rows and writes
// out = fl(fl(q - x) + x) for its pixels (identical formula to the gather
// kernel). Flagged pixels are later overwritten by fixup_kernel.
// Scores bitwise identical to rounds 2-14.
// ---------------------------------------------------------------------------
__global__ __launch_bounds__(512, 4) void vq_main_mfma(const float* __restrict__ x,
                                                       const float* __restrict__ emb,
                                                       const u16* __restrict__ et_hi,
                                                       const u16* __restrict__ et_lo,
                                                       const float* __restrict__ esq,
                                                       int* __restrict__ idx_arr,
                                                       float* __restrict__ m1_arr,
                                                       int* __restrict__ plist,
                                                       int* __restrict__ pcount,
                                                       float* __restrict__ outp) {
    __shared__ __align__(16) char smem[81920];
    // XH [ct4][cg8][row64][8] @0; XL @32768; E / raw-f32 scratch @65536 (16KB)
    float* r_m1 = (float*)(smem + 65536);   // aliases E after the k-loop
    float* r_m2 = (float*)(smem + 69888);
    int*   r_i1 = (int*)(smem + 74240);     // ends at 78592
    int*   idx_sh = (int*)(smem + 78592);   // 64 ints

    const int tid  = threadIdx.x;
    const int lane = tid & 63;
    const int wid  = tid >> 6;        // 0..7
    const int wr   = wid >> 2;        // 0..1 (pixel half)
    const int wc   = wid & 3;         // 0..3 (code quarter)
    const int l15 = lane & 15, l4 = lane >> 4;
    // bijective XCD swizzle: consecutive-on-XCD blocks share the E stream
    const int bid = blockIdx.x;
    const int swz = ((bid & 7) << 7) + (bid >> 3);
    const int p0 = swz * 64;
    const int b   = p0 >> 10;
    const int hw0 = p0 & 1023;

    // ---- fused cvt_x prologue: build XH/XL from f32 x (4 ct phases) ----
    for (int ct = 0; ct < 4; ++ct) {
#pragma unroll
        for (int r = 0; r < 2; ++r) {
            const int task = (r << 9) + tid;        // 0..1023
            const int cl = task >> 4, seg = task & 15;
            const float4 v = *(const float4*)(x + ((size_t)(b * C_ + (ct << 6) + cl)) * HW_ +
                                              hw0 + (seg << 2));
            *(float4*)(smem + 65536 + (cl << 8) + (seg << 4)) = v;
        }
        __syncthreads();
        {
            const int cg = tid >> 6, px = tid & 63;
            u16 h[8], l[8];
#pragma unroll
            for (int i = 0; i < 8; ++i) {
                const float f = *(const float*)(smem + 65536 + (((cg << 3) + i) << 8) + (px << 2));
                h[i] = bf16_rne(f);
                l[i] = bf16_rne(f - bf16_to_f(h[i]));
            }
            *(uint4*)(smem + (ct << 13) + (cg << 10) + (px << 4)) = pack8(h);
            *(uint4*)(smem + 32768 + (ct << 13) + (cg << 10) + (px << 4)) = pack8(l);
        }
        __syncthreads();
    }

    float m1[2], m2[2]; int i1[2];
#pragma unroll
    for (int i = 0; i < 2; ++i) { m1[i] = 3.0e38f; m2[i] = 3.0e38f; i1[i] = 0; }

    for (int kt = 0; kt < 8; ++kt) {
        float4v acc[2][2];
        const float4v zero4 = {0.f, 0.f, 0.f, 0.f};
#pragma unroll
        for (int pf = 0; pf < 2; ++pf)
#pragma unroll
            for (int cf = 0; cf < 2; ++cf) acc[pf][cf] = zero4;

        for (int kg = 0; kg < 8; ++kg) {    // 32-channel steps, ascending
            __syncthreads();                // E free (prev step consumed / prologue done)
            {   // stage E: 8KB hi + 8KB lo, 2 loads/wave
                const size_t ch = (((size_t)((kt << 2) + (kg >> 1))) << 14) + ((size_t)(kg & 1) << 13);
                __builtin_amdgcn_global_load_lds(
                    (gvoid*)((const char*)et_hi + ch + (wid << 10) + (lane << 4)),
                    (lvoid*)(smem + 65536 + (wid << 10)), 16, 0, 0);
                __builtin_amdgcn_global_load_lds(
                    (gvoid*)((const char*)et_lo + ch + (wid << 10) + (lane << 4)),
                    (lvoid*)(smem + 65536 + 8192 + (wid << 10)), 16, 0, 0);
            }
            __syncthreads();                // E landed (vmcnt drained by all waves)

            bf16x8v eh[2], el[2];
#pragma unroll
            for (int cf = 0; cf < 2; ++cf) {
                const int eo = 65536 + (l4 << 11) + (((wc << 5) + (cf << 4) + l15) << 4);
                eh[cf] = *(const bf16x8v*)(smem + eo);
                el[cf] = *(const bf16x8v*)(smem + 8192 + eo);
            }
            const int ct = kg >> 1;
            const int cg = ((kg & 1) << 2) + l4;
#pragma unroll
            for (int pf = 0; pf < 2; ++pf) {
                const int xo = (ct << 13) + (cg << 10) + (((wr << 5) + (pf << 4) + l15) << 4);
                const bf16x8v xh = *(const bf16x8v*)(smem + xo);
                const bf16x8v xl = *(const bf16x8v*)(smem + 32768 + xo);
#pragma unroll
                for (int cf = 0; cf < 2; ++cf) {
                    acc[pf][cf] = __builtin_amdgcn_mfma_f32_16x16x32_bf16(eh[cf], xh, acc[pf][cf], 0, 0, 0);
                    acc[pf][cf] = __builtin_amdgcn_mfma_f32_16x16x32_bf16(eh[cf], xl, acc[pf][cf], 0, 0, 0);
                    acc[pf][cf] = __builtin_amdgcn_mfma_f32_16x16x32_bf16(el[cf], xh, acc[pf][cf], 0, 0, 0);
                }
            }
        }
        // top-2 update; k ascending per pixel slot (cf outer, reg inner)
        const int k0 = kt << 7;
#pragma unroll
        for (int cf = 0; cf < 2; ++cf) {
            const int kb = k0 + (wc << 5) + (cf << 4) + (l4 << 2);
            const float4v ev = *(const float4v*)(esq + kb);
#pragma unroll
            for (int pf = 0; pf < 2; ++pf) {
#pragma unroll
                for (int r = 0; r < 4; ++r) {
                    const float s = fmaf(-2.0f, acc[pf][cf][r], ev[r]);
                    const int k = kb + r;
                    if (s < m1[pf])      { m2[pf] = m1[pf]; m1[pf] = s; i1[pf] = k; }
                    else if (s < m2[pf]) { m2[pf] = s; }
                }
            }
        }
    }

    __syncthreads();    // all E reads done; alias reduction arrays
#pragma unroll
    for (int pf = 0; pf < 2; ++pf) {
        const int p = (wr << 5) + (pf << 4) + l15;   // 0..63
        const int slot = (wc << 2) + l4;             // 0..15
        r_m1[p * 17 + slot] = m1[pf]; r_m2[p * 17 + slot] = m2[pf]; r_i1[p * 17 + slot] = i1[pf];
    }
    __syncthreads();
    if (tid < 64) {
        const int p = tid;
        float M1 = r_m1[p * 17 + 0], M2 = r_m2[p * 17 + 0];
        int   I1 = r_i1[p * 17 + 0];
        for (int t = 1; t < 16; ++t) {
            const float a1 = r_m1[p * 17 + t], a2 = r_m2[p * 17 + t];
            const int   ai = r_i1[p * 17 + t];
            if (a1 < M1 || (a1 == M1 && ai < I1)) { M2 = fminf(M1, a2); M1 = a1; I1 = ai; }
            else                                  { M2 = fminf(M2, a1); }
        }
        const int pix = p0 + p;
        idx_arr[pix] = I1;
        idx_sh[p] = I1;
        m1_arr[pix] = M1;
        if (M2 - M1 <= TAU_FLAG) {
            int pos = atomicAdd(pcount, 1);
            if (pos < MAXFLAG) plist[pos] = pix;
        }
    }

    // ---- optional fused STE out-write (big-ws path): identical formula ----
    if (outp) {
        __syncthreads();
#pragma unroll
        for (int it = 0; it < 32; ++it) {
            const int lin = (it << 9) + tid;   // 0..16383
            const int c = lin >> 6, px = lin & 63;
            const size_t o = ((size_t)(b * C_ + c)) * HW_ + hw0 + px;
            const float q  = emb[(size_t)idx_sh[px] * C_ + c];
            const float xv = x[o];
            outp[o] = fadd_x(fsub_x(q, xv), xv);
        }
    }
}

// ---------------------------------------------------------------------------
// gather_x v2 (unchanged): 8 flagged slots per block; emits xg, xsq,
// best-init and the bf16 xgt tiles directly.
// ---------------------------------------------------------------------------
__global__ __launch_bounds__(256) void gather_x_kernel(const float* __restrict__ x,
                                                       const int* __restrict__ plist,
                                                       const int* __restrict__ pcount,
                                                       float* __restrict__ xg,
                                                       float* __restrict__ xsq_arr,
                                                       u64* __restrict__ best_arr,
                                                       u16* __restrict__ xgt_hi,
                                                       u16* __restrict__ xgt_lo) {
    __shared__ float xs[8][264];
    __shared__ float rsum[8][16];
    __shared__ int pix_s[8];
    const int nflag = min(*pcount, MAXFLAG);
    const int sbase = blockIdx.x << 3;
    if (sbase >= nflag) return;
    const int nact = min(8, nflag - sbase);
    const int tid = threadIdx.x;

    if (tid < 8) pix_s[tid] = (tid < nact) ? plist[sbase + tid] : plist[sbase];
    __syncthreads();
#pragma unroll
    for (int p = 0; p < 8; ++p) {       // 8 independent scattered loads in flight
        const int pix = pix_s[p];
        const int b = pix >> 10, hw = pix & 1023;
        const float v = x[((size_t)(b * C_ + tid)) * HW_ + hw];
        xs[p][tid] = v;
        if (p < nact) xg[(size_t)(sbase + p) * C_ + tid] = v;
    }
    __syncthreads();
    if (tid < 128) {                    // 8 slots x 16 chains, exact np tree
        const int p = tid >> 4, h = (tid >> 3) & 1, j = tid & 7;
        const float* q = &xs[p][h * 128];
        float r = fmul_x(q[j], q[j]);
        for (int i = 8; i < 128; i += 8) r = fadd_x(r, fmul_x(q[i + j], q[i + j]));
        rsum[p][h * 8 + j] = r;
    }
    __syncthreads();
    if (tid < 8 && tid < nact) {
        const float* r0 = &rsum[tid][0];
        const float h0 = fadd_x(fadd_x(fadd_x(r0[0], r0[1]), fadd_x(r0[2], r0[3])),
                                fadd_x(fadd_x(r0[4], r0[5]), fadd_x(r0[6], r0[7])));
        const float h1 = fadd_x(fadd_x(fadd_x(r0[8], r0[9]), fadd_x(r0[10], r0[11])),
                                fadd_x(fadd_x(r0[12], r0[13]), fadd_x(r0[14], r0[15])));
        xsq_arr[sbase + tid] = fadd_x(h0, h1);
        best_arr[sbase + tid] = ~0ull;
    }
    // emit bf16 staged tiles (identical values & layout)
    {
        const int p  = tid >> 5;            // 0..7
        const int ct = (tid >> 3) & 3;      // 0..3
        const int cg = tid & 7;             // 0..7
        if (p < nact) {
            const int s  = sbase + p;
            const int sb = s >> 7;
            const int sr = s & 127;
            const int c = (ct << 6) + (cg << 3);
            u16 h[8], l[8];
#pragma unroll
            for (int i = 0; i < 8; ++i) {
                const float f = xs[p][c + i];
                h[i] = bf16_rne(f);
                l[i] = bf16_rne(f - bf16_to_f(h[i]));
            }
            const size_t off = ((size_t)((sb << 2) + ct) << 13) + (cg << 10) + (sr << 3);
            *(uint4*)(xgt_hi + off) = pack8(h);
            *(uint4*)(xgt_lo + off) = pack8(l);
        }
    }
}

// ---------------------------------------------------------------------------
// MFMA scan of flagged slots (unchanged): 128 slots x 128 codes per block;
// candidates appended to a global list.
// ---------------------------------------------------------------------------
__global__ __launch_bounds__(256) void vq_scan_mfma(const u16* __restrict__ xgt_hi,
                                                    const u16* __restrict__ xgt_lo,
                                                    const u16* __restrict__ et_hi,
                                                    const u16* __restrict__ et_lo,
                                                    const float* __restrict__ esq,
                                                    const float* __restrict__ m1_arr,
                                                    const int* __restrict__ plist,
                                                    const int* __restrict__ pcount,
                                                    u32* __restrict__ cand,
                                                    int* __restrict__ ccount) {
    __shared__ __align__(16) u16 xsb_hi[8192], xsb_lo[8192], esb_hi[8192], esb_lo[8192];
    __shared__ float thresh_s[128];

    const int nflag = min(*pcount, MAXFLAG);
    const int st = blockIdx.x >> 3;     // slot tile
    const int kt = blockIdx.x & 7;      // code tile
    const int p0 = st << 7;
    if (p0 >= nflag) return;
    const int tid = threadIdx.x;
    if (tid < 128) {
        const int s = p0 + tid;
        thresh_s[tid] = (s < nflag) ? (m1_arr[plist[s]] + CAND_MARGIN) : -3.0e38f;
    }

    const int lane = tid & 63;
    const int wid  = tid >> 6;
    const int wr = wid >> 1, wc = wid & 1;
    const int l15 = lane & 15, l4 = lane >> 4;

    const char* xhb = (const char*)xgt_hi + ((size_t)st << 16);
    const char* xlb = (const char*)xgt_lo + ((size_t)st << 16);
    const char* ehb = (const char*)et_hi + ((size_t)(kt << 2) << 14);
    const char* elb = (const char*)et_lo + ((size_t)(kt << 2) << 14);

    float4v acc[4][4];
    const float4v zero4 = {0.f, 0.f, 0.f, 0.f};
#pragma unroll
    for (int pf = 0; pf < 4; ++pf)
#pragma unroll
        for (int cf = 0; cf < 4; ++cf) acc[pf][cf] = zero4;

    for (int ct = 0; ct < 4; ++ct) {
        const int coff = ct << 14;
        __syncthreads();
#pragma unroll
        for (int i = 0; i < 4; ++i) {
            const int off = (((i << 2) + wid) << 10);
            const int src = off + (lane << 4);
            __builtin_amdgcn_global_load_lds((gvoid*)(xhb + coff + src),
                (lvoid*)((char*)xsb_hi + off), 16, 0, 0);
            __builtin_amdgcn_global_load_lds((gvoid*)(xlb + coff + src),
                (lvoid*)((char*)xsb_lo + off), 16, 0, 0);
            __builtin_amdgcn_global_load_lds((gvoid*)(ehb + coff + src),
                (lvoid*)((char*)esb_hi + off), 16, 0, 0);
            __builtin_amdgcn_global_load_lds((gvoid*)(elb + coff + src),
                (lvoid*)((char*)esb_lo + off), 16, 0, 0);
        }
        __syncthreads();
#pragma unroll
        for (int ks = 0; ks < 2; ++ks) {
            const int cgb = (ks << 2) + l4;
            const int ebase = (cgb << 7) + (wc << 6) + l15;
            const int xbase = (cgb << 7) + (wr << 6) + l15;
            bf16x8v eh[4], el[4];
#pragma unroll
            for (int cf = 0; cf < 4; ++cf) {
                const int eo = (ebase + (cf << 4)) << 3;
                eh[cf] = *(const bf16x8v*)(esb_hi + eo);
                el[cf] = *(const bf16x8v*)(esb_lo + eo);
            }
#pragma unroll
            for (int pf = 0; pf < 4; ++pf) {
                const int xo = (xbase + (pf << 4)) << 3;
                const bf16x8v xh = *(const bf16x8v*)(xsb_hi + xo);
                const bf16x8v xl = *(const bf16x8v*)(xsb_lo + xo);
#pragma unroll
                for (int cf = 0; cf < 4; ++cf) {
                    acc[pf][cf] = __builtin_amdgcn_mfma_f32_16x16x32_bf16(eh[cf], xh, acc[pf][cf], 0, 0, 0);
                    acc[pf][cf] = __builtin_amdgcn_mfma_f32_16x16x32_bf16(eh[cf], xl, acc[pf][cf], 0, 0, 0);
                    acc[pf][cf] = __builtin_amdgcn_mfma_f32_16x16x32_bf16(el[cf], xh, acc[pf][cf], 0, 0, 0);
                }
            }
        }
    }

    const int k0 = kt << 7;
#pragma unroll
    for (int cf = 0; cf < 4; ++cf) {
        const int kb = k0 + (wc << 6) + (cf << 4) + (l4 << 2);
        const float4v ev = *(const float4v*)(esq + kb);
#pragma unroll
        for (int pf = 0; pf < 4; ++pf) {
            const int slotl = (wr << 6) + (pf << 4) + l15;
            const int slotg = p0 + slotl;
            if (slotg < nflag) {
                const float th = thresh_s[slotl];
#pragma unroll
                for (int r = 0; r < 4; ++r) {
                    const float s = fmaf(-2.0f, acc[pf][cf][r], ev[r]);
                    if (s <= th) {
                        int pos = atomicAdd(ccount, 1);
                        if (pos < MAXCAND) cand[pos] = ((u32)slotg << 10) | (u32)(kb + r);
                    }
                }
            }
        }
    }
}

// ---------------------------------------------------------------------------
// Exact np rescore: one thread per candidate (unchanged).
// ---------------------------------------------------------------------------
__global__ __launch_bounds__(256) void vq_cand_np(const float* __restrict__ xg,
                                                  const float* __restrict__ emb,
                                                  const float* __restrict__ esq,
                                                  const float* __restrict__ xsq_arr,
                                                  const u32* __restrict__ cand,
                                                  const int* __restrict__ ccount,
                                                  u64* __restrict__ best_arr) {
    const int ncand = min(*ccount, MAXCAND);
    const int id = blockIdx.x * 256 + threadIdx.x;
    if (id >= ncand) return;
    const u32 v = cand[id];
    const int slot = (int)(v >> 10);
    const int k = (int)(v & 1023u);
    const float cr = np_einsum_dot_256(xg + (size_t)slot * C_, emb + (size_t)k * C_);
    const float d2 = fadd_x(fsub_x(xsq_arr[slot], fmul_x(2.0f, cr)), esq[k]);
    const u64 pk = ((u64)__float_as_uint(d2) << 32) | (unsigned)k;
    atomicMin(&best_arr[slot], pk);
}

// finalize (small-ws path only): write rescue winners into idx_arr.
__global__ __launch_bounds__(256) void finalize_kernel(const u64* __restrict__ best_arr,
                                                       const int* __restrict__ plist,
                                                       const int* __restrict__ pcount,
                                                       int* __restrict__ idx_arr) {
    const int nflag = min(*pcount, MAXFLAG);
    const int s = blockIdx.x * 256 + threadIdx.x;
    if (s >= nflag) return;
    idx_arr[plist[s]] = (int)(best_arr[s] & 0xffffffffu);
}

// ---------------------------------------------------------------------------
// fixup (big-ws path): rewrite flagged pixels' out columns with the rescue
// winner. xv comes from xg (bitwise-identical copy of x); formula identical
// to the gather/epilogue STE write.
// ---------------------------------------------------------------------------
__global__ __launch_bounds__(256) void fixup_kernel(const float* __restrict__ xg,
                                                    const float* __restrict__ emb,
                                                    const u64* __restrict__ best_arr,
                                                    const int* __restrict__ plist,
                                                    const int* __restrict__ pcount,
                                                    float* __restrict__ out) {
    const int nflag = min(*pcount, MAXFLAG);
    const int s = blockIdx.x;
    if (s >= nflag) return;
    const int tid = threadIdx.x;
    const int pix = plist[s];
    const int b = pix >> 10, hw = pix & 1023;
    const int winner = (int)(best_arr[s] & 0xffffffffu);
    const float q  = emb[(size_t)winner * C_ + tid];
    const float xv = xg[(size_t)s * C_ + tid];
    out[((size_t)(b * C_ + tid)) * HW_ + hw] = fadd_x(fsub_x(q, xv), xv);
}

// ---------------------------------------------------------------------------
// gather + STE (small-ws fallback path only; unchanged).
// ---------------------------------------------------------------------------
__global__ __launch_bounds__(256) void gather_kernel(const float* __restrict__ x,
                                                     const float* __restrict__ emb,
                                                     const int* __restrict__ idx_arr,
                                                     float* __restrict__ out) {
    __shared__ int idx_s[128];
    __shared__ float qs[32][257];
    const int tid = threadIdx.x;
    const int blk = blockIdx.x;
    const int b   = blk >> 3;
    const int hw0 = (blk & 7) << 7;
    if (tid < 128) idx_s[tid] = idx_arr[blk * 128 + tid];
    __syncthreads();
    const int cidx = tid >> 5;          // 0..7
    const int px   = tid & 31;          // 0..31
    for (int ch = 0; ch < 4; ++ch) {
        const int p0c = ch << 5;
#pragma unroll 8
        for (int r = 0; r < 32; ++r)
            qs[r][tid] = emb[(size_t)idx_s[p0c + r] * C_ + tid];
        __syncthreads();
#pragma unroll
        for (int j = 0; j < 32; ++j) {
            const int c = (j << 3) + cidx;
            const size_t o = ((size_t)b * C_ + c) * HW_ + hw0 + p0c + px;
            const float q  = qs[px][c];
            const float xv = x[o];
            out[o] = fadd_x(fsub_x(q, xv), xv);
        }
        __syncthreads();
    }
}

extern "C" void kernel_launch(void* const* d_in, const int* in_sizes, int n_in,
                              void* d_out, int out_size, void* d_ws, size_t ws_size,
                              hipStream_t stream) {
    const float* x   = (const float*)d_in[0];
    const float* emb = (const float*)d_in[1];
    float* out = (float*)d_out;
    char* ws = (char*)d_ws;

    float* esq     = (float*)ws;                 // 4 KB
    int*   pcount  = (int*)(ws + 4096);
    int*   ccount  = (int*)(ws + 8192);
    int*   plist   = (int*)(ws + 12288);         // 32 KB
    float* m1_arr  = (float*)(ws + 65536);       // 256 KB
    int*   idx_arr = (int*)(ws + 327680);        // 256 KB
    float* xsq_arr = (float*)(ws + 589824);      // 32 KB
    u64*   best_arr= (u64*)(ws + 622592);        // 64 KB
    u32*   cand    = (u32*)(ws + 688128);        // 256 KB
    u16*   et_hi   = (u16*)(ws + 983040);        // 512 KB (tiled layout)
    u16*   et_lo   = (u16*)(ws + 1507328);       // 512 KB (base ends ~2 MB)

    // Rescue scratch: workspace if it fits (enables fused out-write in main,
    // deleting the standalone gather pass); else hosted in the out buffer
    // (round-14 fallback: main skips the out-write, gather runs last).
    const bool bigws = ws_size >= (size_t)(2097152 + (16u << 20));
    float* xg;
    u16 *xgt_hi, *xgt_lo;
    if (bigws) {
        xg     = (float*)(ws + 2097152);                      // 8 MB
        xgt_hi = (u16*)(ws + 2097152 + (8u << 20));           // 4 MB
        xgt_lo = (u16*)(ws + 2097152 + (12u << 20));          // 4 MB
    } else {
        xg     = (float*)d_out;                               // 8 MB
        xgt_hi = (u16*)((char*)d_out + (8u << 20));           // 4 MB
        xgt_lo = (u16*)((char*)d_out + (12u << 20));          // 4 MB
    }

    prep_e_kernel<<<K_ / 32, 256, 0, stream>>>(emb, esq, et_hi, et_lo, pcount, ccount);
    vq_main_mfma<<<NPIX / 64, 512, 0, stream>>>(x, emb, et_hi, et_lo, esq,
                                                idx_arr, m1_arr, plist, pcount,
                                                bigws ? out : (float*)nullptr);
    gather_x_kernel<<<MAXFLAG / 8, 256, 0, stream>>>(x, plist, pcount, xg, xsq_arr,
                                                     best_arr, xgt_hi, xgt_lo);
    vq_scan_mfma<<<(MAXFLAG / 128) * 8, 256, 0, stream>>>(xgt_hi, xgt_lo, et_hi, et_lo,
                                                          esq, m1_arr, plist, pcount,
                                                          cand, ccount);
    vq_cand_np<<<MAXCAND / 256, 256, 0, stream>>>(xg, emb, esq, xsq_arr, cand, ccount,
                                                  best_arr);
    if (bigws) {
        fixup_kernel<<<MAXFLAG, 256, 0, stream>>>(xg, emb, best_arr, plist, pcount, out);
    } else {
        finalize_kernel<<<MAXFLAG / 256, 256, 0, stream>>>(best_arr, plist, pcount, idx_arr);
        gather_kernel<<<NPIX / 128, 256, 0, stream>>>(x, emb, idx_arr, out);
    }
}

// Round 16
// 298.614 us; speedup vs baseline: 1.1913x; 1.1913x over previous
//
#include <hip/hip_runtime.h>

#define B_    64
#define C_    256
#define HW_   1024
#define NPIX  (B_ * HW_)
#define K_    1024
#define TAU_FLAG    2.0e-4f
#define CAND_MARGIN 2.2e-4f
#define MAXFLAG     8192
#define MAXCAND     65536

typedef unsigned short u16;
typedef unsigned int   u32;
typedef unsigned long long u64;
typedef __attribute__((ext_vector_type(8))) __bf16 bf16x8v;
typedef __attribute__((ext_vector_type(4))) float  float4v;
typedef __attribute__((address_space(1))) void gvoid;
typedef __attribute__((address_space(3))) void lvoid;

// Rounding barriers: force a separately-rounded f32 mul/add/sub (defeat
// -ffp-contract=fast fusion and any reassociation across the boundary).
__device__ __forceinline__ float fmul_x(float a, float b) { float p = a * b; asm volatile("" : "+v"(p)); return p; }
__device__ __forceinline__ float fadd_x(float a, float b) { float s = a + b; asm volatile("" : "+v"(s)); return s; }
__device__ __forceinline__ float fsub_x(float a, float b) { float s = a - b; asm volatile("" : "+v"(s)); return s; }

// f32 -> bf16 round-to-nearest-even (finite inputs only), and back.
__device__ __forceinline__ u16 bf16_rne(float f) {
    u32 u = __float_as_uint(f);
    u32 r = u + 0x7FFFu + ((u >> 16) & 1u);
    return (u16)(r >> 16);
}
__device__ __forceinline__ float bf16_to_f(u16 h) { return __uint_as_float(((u32)h) << 16); }

__device__ __forceinline__ uint4 pack8(const u16* h) {
    return make_uint4((u32)h[0] | ((u32)h[1] << 16), (u32)h[2] | ((u32)h[3] << 16),
                      (u32)h[4] | ((u32)h[5] << 16), (u32)h[6] | ((u32)h[7] << 16));
}

// ---------------------------------------------------------------------------
// numpy pairwise sum replica for 256 contiguous squares (unchanged).
// ---------------------------------------------------------------------------
__device__ __forceinline__ float np_sumsq_256(const float* __restrict__ a) {
    float half[2];
#pragma unroll
    for (int h = 0; h < 2; ++h) {
        const float* p = a + h * 128;
        float r[8];
#pragma unroll
        for (int j = 0; j < 8; ++j) r[j] = fmul_x(p[j], p[j]);
        for (int i = 8; i < 128; i += 8)
#pragma unroll
            for (int j = 0; j < 8; ++j) r[j] = fadd_x(r[j], fmul_x(p[i + j], p[i + j]));
        half[h] = fadd_x(fadd_x(fadd_x(r[0], r[1]), fadd_x(r[2], r[3])),
                         fadd_x(fadd_x(r[4], r[5]), fadd_x(r[6], r[7])));
    }
    return fadd_x(half[0], half[1]);
}

// ---------------------------------------------------------------------------
// numpy einsum f32 dot replica (unchanged).
// ---------------------------------------------------------------------------
__device__ float np_einsum_dot_256(const float* __restrict__ xr,
                                   const float* __restrict__ er) {
    float acc0 = 0.f, acc1 = 0.f, acc2 = 0.f, acc3 = 0.f;
    for (int blk = 0; blk < 256; blk += 16) {
#pragma unroll
        for (int sub = 3; sub >= 0; --sub) {
            const int base = blk + sub * 4;
            acc0 = fadd_x(acc0, fmul_x(xr[base + 0], er[base + 0]));
            acc1 = fadd_x(acc1, fmul_x(xr[base + 1], er[base + 1]));
            acc2 = fadd_x(acc2, fmul_x(xr[base + 2], er[base + 2]));
            acc3 = fadd_x(acc3, fmul_x(xr[base + 3], er[base + 3]));
        }
    }
    return fadd_x(fadd_x(acc0, acc2), fadd_x(acc1, acc3));
}

// ---------------------------------------------------------------------------
// prep_e: zero counters + e_sq (np-pairwise replica) + emb -> hi/lo bf16
// staged tiles (verbatim bodies). Grid 32 x 256.
// ---------------------------------------------------------------------------
__global__ __launch_bounds__(256) void prep_e_kernel(const float* __restrict__ emb,
                                                     float* __restrict__ esq,
                                                     u16* __restrict__ et_hi,
                                                     u16* __restrict__ et_lo,
                                                     int* pcount, int* ccount) {
    const int tid = threadIdx.x;
    if (blockIdx.x == 0 && tid == 0) { *pcount = 0; *ccount = 0; }
    const int k  = (blockIdx.x << 5) + (tid & 31);
    const int cg = tid >> 5;
    const int kb = k >> 7;
    const int kr = k & 127;
#pragma unroll
    for (int ct = 0; ct < 4; ++ct) {
        const int c = (ct << 6) + (cg << 3);
        const float* src = emb + (size_t)k * C_ + c;
        u16 h[8], l[8];
#pragma unroll
        for (int i = 0; i < 8; ++i) {
            const float f = src[i];
            h[i] = bf16_rne(f);
            l[i] = bf16_rne(f - bf16_to_f(h[i]));
        }
        const size_t off = ((size_t)((kb << 2) + ct) << 13) + (cg << 10) + (kr << 3);
        *(uint4*)(et_hi + off) = pack8(h);
        *(uint4*)(et_lo + off) = pack8(l);
    }
    if (tid < 32) {
        const int row = (blockIdx.x << 5) + tid;
        esq[row] = np_sumsq_256(emb + (size_t)row * C_);
    }
}

// ---------------------------------------------------------------------------
// MFMA bf16x3 scoring + top-2 + flag. Verbatim round-14 kernel (best
// measured: r8 schedule + fused cvt_x, 139 us). Scores bitwise identical
// to rounds 2-15. 512 threads, 64 px x 1024 codes; LDS 80KB; 2 blocks/CU.
// ---------------------------------------------------------------------------
__global__ __launch_bounds__(512, 4) void vq_main_mfma(const float* __restrict__ x,
                                                       const u16* __restrict__ et_hi,
                                                       const u16* __restrict__ et_lo,
                                                       const float* __restrict__ esq,
                                                       int* __restrict__ idx_arr,
                                                       float* __restrict__ m1_arr,
                                                       int* __restrict__ plist,
                                                       int* __restrict__ pcount) {
    __shared__ __align__(16) char smem[81920];
    // XH [ct4][cg8][row64][8] @0; XL @32768; E / raw-f32 scratch @65536 (16KB)
    float* r_m1 = (float*)(smem + 65536);   // aliases E after the k-loop
    float* r_m2 = (float*)(smem + 69888);
    int*   r_i1 = (int*)(smem + 74240);

    const int tid  = threadIdx.x;
    const int lane = tid & 63;
    const int wid  = tid >> 6;        // 0..7
    const int wr   = wid >> 2;        // 0..1 (pixel half)
    const int wc   = wid & 3;         // 0..3 (code quarter)
    const int l15 = lane & 15, l4 = lane >> 4;
    // bijective XCD swizzle: consecutive-on-XCD blocks share the E stream
    const int bid = blockIdx.x;
    const int swz = ((bid & 7) << 7) + (bid >> 3);
    const int p0 = swz * 64;
    const int b   = p0 >> 10;
    const int hw0 = p0 & 1023;

    // ---- fused cvt_x prologue: build XH/XL from f32 x (4 ct phases) ----
    for (int ct = 0; ct < 4; ++ct) {
#pragma unroll
        for (int r = 0; r < 2; ++r) {
            const int task = (r << 9) + tid;        // 0..1023
            const int cl = task >> 4, seg = task & 15;
            const float4 v = *(const float4*)(x + ((size_t)(b * C_ + (ct << 6) + cl)) * HW_ +
                                              hw0 + (seg << 2));
            *(float4*)(smem + 65536 + (cl << 8) + (seg << 4)) = v;
        }
        __syncthreads();
        {
            const int cg = tid >> 6, px = tid & 63;
            u16 h[8], l[8];
#pragma unroll
            for (int i = 0; i < 8; ++i) {
                const float f = *(const float*)(smem + 65536 + (((cg << 3) + i) << 8) + (px << 2));
                h[i] = bf16_rne(f);
                l[i] = bf16_rne(f - bf16_to_f(h[i]));
            }
            *(uint4*)(smem + (ct << 13) + (cg << 10) + (px << 4)) = pack8(h);
            *(uint4*)(smem + 32768 + (ct << 13) + (cg << 10) + (px << 4)) = pack8(l);
        }
        __syncthreads();
    }

    float m1[2], m2[2]; int i1[2];
#pragma unroll
    for (int i = 0; i < 2; ++i) { m1[i] = 3.0e38f; m2[i] = 3.0e38f; i1[i] = 0; }

    for (int kt = 0; kt < 8; ++kt) {
        float4v acc[2][2];
        const float4v zero4 = {0.f, 0.f, 0.f, 0.f};
#pragma unroll
        for (int pf = 0; pf < 2; ++pf)
#pragma unroll
            for (int cf = 0; cf < 2; ++cf) acc[pf][cf] = zero4;

        for (int kg = 0; kg < 8; ++kg) {    // 32-channel steps, ascending
            __syncthreads();                // E free (prev step consumed / prologue done)
            {   // stage E: 8KB hi + 8KB lo, 2 loads/wave
                const size_t ch = (((size_t)((kt << 2) + (kg >> 1))) << 14) + ((size_t)(kg & 1) << 13);
                __builtin_amdgcn_global_load_lds(
                    (gvoid*)((const char*)et_hi + ch + (wid << 10) + (lane << 4)),
                    (lvoid*)(smem + 65536 + (wid << 10)), 16, 0, 0);
                __builtin_amdgcn_global_load_lds(
                    (gvoid*)((const char*)et_lo + ch + (wid << 10) + (lane << 4)),
                    (lvoid*)(smem + 65536 + 8192 + (wid << 10)), 16, 0, 0);
            }
            __syncthreads();                // E landed (vmcnt drained by all waves)

            bf16x8v eh[2], el[2];
#pragma unroll
            for (int cf = 0; cf < 2; ++cf) {
                const int eo = 65536 + (l4 << 11) + (((wc << 5) + (cf << 4) + l15) << 4);
                eh[cf] = *(const bf16x8v*)(smem + eo);
                el[cf] = *(const bf16x8v*)(smem + 8192 + eo);
            }
            const int ct = kg >> 1;
            const int cg = ((kg & 1) << 2) + l4;
#pragma unroll
            for (int pf = 0; pf < 2; ++pf) {
                const int xo = (ct << 13) + (cg << 10) + (((wr << 5) + (pf << 4) + l15) << 4);
                const bf16x8v xh = *(const bf16x8v*)(smem + xo);
                const bf16x8v xl = *(const bf16x8v*)(smem + 32768 + xo);
#pragma unroll
                for (int cf = 0; cf < 2; ++cf) {
                    acc[pf][cf] = __builtin_amdgcn_mfma_f32_16x16x32_bf16(eh[cf], xh, acc[pf][cf], 0, 0, 0);
                    acc[pf][cf] = __builtin_amdgcn_mfma_f32_16x16x32_bf16(eh[cf], xl, acc[pf][cf], 0, 0, 0);
                    acc[pf][cf] = __builtin_amdgcn_mfma_f32_16x16x32_bf16(el[cf], xh, acc[pf][cf], 0, 0, 0);
                }
            }
        }
        // top-2 update; k ascending per pixel slot (cf outer, reg inner)
        const int k0 = kt << 7;
#pragma unroll
        for (int cf = 0; cf < 2; ++cf) {
            const int kb = k0 + (wc << 5) + (cf << 4) + (l4 << 2);
            const float4v ev = *(const float4v*)(esq + kb);
#pragma unroll
            for (int pf = 0; pf < 2; ++pf) {
#pragma unroll
                for (int r = 0; r < 4; ++r) {
                    const float s = fmaf(-2.0f, acc[pf][cf][r], ev[r]);
                    const int k = kb + r;
                    if (s < m1[pf])      { m2[pf] = m1[pf]; m1[pf] = s; i1[pf] = k; }
                    else if (s < m2[pf]) { m2[pf] = s; }
                }
            }
        }
    }

    __syncthreads();    // all E reads done; alias reduction arrays
#pragma unroll
    for (int pf = 0; pf < 2; ++pf) {
        const int p = (wr << 5) + (pf << 4) + l15;   // 0..63
        const int slot = (wc << 2) + l4;             // 0..15
        r_m1[p * 17 + slot] = m1[pf]; r_m2[p * 17 + slot] = m2[pf]; r_i1[p * 17 + slot] = i1[pf];
    }
    __syncthreads();
    if (tid < 64) {
        const int p = tid;
        float M1 = r_m1[p * 17 + 0], M2 = r_m2[p * 17 + 0];
        int   I1 = r_i1[p * 17 + 0];
        for (int t = 1; t < 16; ++t) {
            const float a1 = r_m1[p * 17 + t], a2 = r_m2[p * 17 + t];
            const int   ai = r_i1[p * 17 + t];
            if (a1 < M1 || (a1 == M1 && ai < I1)) { M2 = fminf(M1, a2); M1 = a1; I1 = ai; }
            else                                  { M2 = fminf(M2, a1); }
        }
        const int pix = p0 + p;
        idx_arr[pix] = I1;
        m1_arr[pix] = M1;
        if (M2 - M1 <= TAU_FLAG) {
            int pos = atomicAdd(pcount, 1);
            if (pos < MAXFLAG) plist[pos] = pix;
        }
    }
}

// ---------------------------------------------------------------------------
// gather_x v2 (unchanged): 8 flagged slots per block; emits xg, xsq,
// best-init and the bf16 xgt tiles directly.
// ---------------------------------------------------------------------------
__global__ __launch_bounds__(256) void gather_x_kernel(const float* __restrict__ x,
                                                       const int* __restrict__ plist,
                                                       const int* __restrict__ pcount,
                                                       float* __restrict__ xg,
                                                       float* __restrict__ xsq_arr,
                                                       u64* __restrict__ best_arr,
                                                       u16* __restrict__ xgt_hi,
                                                       u16* __restrict__ xgt_lo) {
    __shared__ float xs[8][264];
    __shared__ float rsum[8][16];
    __shared__ int pix_s[8];
    const int nflag = min(*pcount, MAXFLAG);
    const int sbase = blockIdx.x << 3;
    if (sbase >= nflag) return;
    const int nact = min(8, nflag - sbase);
    const int tid = threadIdx.x;

    if (tid < 8) pix_s[tid] = (tid < nact) ? plist[sbase + tid] : plist[sbase];
    __syncthreads();
#pragma unroll
    for (int p = 0; p < 8; ++p) {       // 8 independent scattered loads in flight
        const int pix = pix_s[p];
        const int b = pix >> 10, hw = pix & 1023;
        const float v = x[((size_t)(b * C_ + tid)) * HW_ + hw];
        xs[p][tid] = v;
        if (p < nact) xg[(size_t)(sbase + p) * C_ + tid] = v;
    }
    __syncthreads();
    if (tid < 128) {                    // 8 slots x 16 chains, exact np tree
        const int p = tid >> 4, h = (tid >> 3) & 1, j = tid & 7;
        const float* q = &xs[p][h * 128];
        float r = fmul_x(q[j], q[j]);
        for (int i = 8; i < 128; i += 8) r = fadd_x(r, fmul_x(q[i + j], q[i + j]));
        rsum[p][h * 8 + j] = r;
    }
    __syncthreads();
    if (tid < 8 && tid < nact) {
        const float* r0 = &rsum[tid][0];
        const float h0 = fadd_x(fadd_x(fadd_x(r0[0], r0[1]), fadd_x(r0[2], r0[3])),
                                fadd_x(fadd_x(r0[4], r0[5]), fadd_x(r0[6], r0[7])));
        const float h1 = fadd_x(fadd_x(fadd_x(r0[8], r0[9]), fadd_x(r0[10], r0[11])),
                                fadd_x(fadd_x(r0[12], r0[13]), fadd_x(r0[14], r0[15])));
        xsq_arr[sbase + tid] = fadd_x(h0, h1);
        best_arr[sbase + tid] = ~0ull;
    }
    // emit bf16 staged tiles (identical values & layout)
    {
        const int p  = tid >> 5;            // 0..7
        const int ct = (tid >> 3) & 3;      // 0..3
        const int cg = tid & 7;             // 0..7
        if (p < nact) {
            const int s  = sbase + p;
            const int sb = s >> 7;
            const int sr = s & 127;
            const int c = (ct << 6) + (cg << 3);
            u16 h[8], l[8];
#pragma unroll
            for (int i = 0; i < 8; ++i) {
                const float f = xs[p][c + i];
                h[i] = bf16_rne(f);
                l[i] = bf16_rne(f - bf16_to_f(h[i]));
            }
            const size_t off = ((size_t)((sb << 2) + ct) << 13) + (cg << 10) + (sr << 3);
            *(uint4*)(xgt_hi + off) = pack8(h);
            *(uint4*)(xgt_lo + off) = pack8(l);
        }
    }
}

// ---------------------------------------------------------------------------
// MFMA scan of flagged slots (unchanged): 128 slots x 128 codes per block;
// candidates appended to a global list.
// ---------------------------------------------------------------------------
__global__ __launch_bounds__(256) void vq_scan_mfma(const u16* __restrict__ xgt_hi,
                                                    const u16* __restrict__ xgt_lo,
                                                    const u16* __restrict__ et_hi,
                                                    const u16* __restrict__ et_lo,
                                                    const float* __restrict__ esq,
                                                    const float* __restrict__ m1_arr,
                                                    const int* __restrict__ plist,
                                                    const int* __restrict__ pcount,
                                                    u32* __restrict__ cand,
                                                    int* __restrict__ ccount) {
    __shared__ __align__(16) u16 xsb_hi[8192], xsb_lo[8192], esb_hi[8192], esb_lo[8192];
    __shared__ float thresh_s[128];

    const int nflag = min(*pcount, MAXFLAG);
    const int st = blockIdx.x >> 3;     // slot tile
    const int kt = blockIdx.x & 7;      // code tile
    const int p0 = st << 7;
    if (p0 >= nflag) return;
    const int tid = threadIdx.x;
    if (tid < 128) {
        const int s = p0 + tid;
        thresh_s[tid] = (s < nflag) ? (m1_arr[plist[s]] + CAND_MARGIN) : -3.0e38f;
    }

    const int lane = tid & 63;
    const int wid  = tid >> 6;
    const int wr = wid >> 1, wc = wid & 1;
    const int l15 = lane & 15, l4 = lane >> 4;

    const char* xhb = (const char*)xgt_hi + ((size_t)st << 16);
    const char* xlb = (const char*)xgt_lo + ((size_t)st << 16);
    const char* ehb = (const char*)et_hi + ((size_t)(kt << 2) << 14);
    const char* elb = (const char*)et_lo + ((size_t)(kt << 2) << 14);

    float4v acc[4][4];
    const float4v zero4 = {0.f, 0.f, 0.f, 0.f};
#pragma unroll
    for (int pf = 0; pf < 4; ++pf)
#pragma unroll
        for (int cf = 0; cf < 4; ++cf) acc[pf][cf] = zero4;

    for (int ct = 0; ct < 4; ++ct) {
        const int coff = ct << 14;
        __syncthreads();
#pragma unroll
        for (int i = 0; i < 4; ++i) {
            const int off = (((i << 2) + wid) << 10);
            const int src = off + (lane << 4);
            __builtin_amdgcn_global_load_lds((gvoid*)(xhb + coff + src),
                (lvoid*)((char*)xsb_hi + off), 16, 0, 0);
            __builtin_amdgcn_global_load_lds((gvoid*)(xlb + coff + src),
                (lvoid*)((char*)xsb_lo + off), 16, 0, 0);
            __builtin_amdgcn_global_load_lds((gvoid*)(ehb + coff + src),
                (lvoid*)((char*)esb_hi + off), 16, 0, 0);
            __builtin_amdgcn_global_load_lds((gvoid*)(elb + coff + src),
                (lvoid*)((char*)esb_lo + off), 16, 0, 0);
        }
        __syncthreads();
#pragma unroll
        for (int ks = 0; ks < 2; ++ks) {
            const int cgb = (ks << 2) + l4;
            const int ebase = (cgb << 7) + (wc << 6) + l15;
            const int xbase = (cgb << 7) + (wr << 6) + l15;
            bf16x8v eh[4], el[4];
#pragma unroll
            for (int cf = 0; cf < 4; ++cf) {
                const int eo = (ebase + (cf << 4)) << 3;
                eh[cf] = *(const bf16x8v*)(esb_hi + eo);
                el[cf] = *(const bf16x8v*)(esb_lo + eo);
            }
#pragma unroll
            for (int pf = 0; pf < 4; ++pf) {
                const int xo = (xbase + (pf << 4)) << 3;
                const bf16x8v xh = *(const bf16x8v*)(xsb_hi + xo);
                const bf16x8v xl = *(const bf16x8v*)(xsb_lo + xo);
#pragma unroll
                for (int cf = 0; cf < 4; ++cf) {
                    acc[pf][cf] = __builtin_amdgcn_mfma_f32_16x16x32_bf16(eh[cf], xh, acc[pf][cf], 0, 0, 0);
                    acc[pf][cf] = __builtin_amdgcn_mfma_f32_16x16x32_bf16(eh[cf], xl, acc[pf][cf], 0, 0, 0);
                    acc[pf][cf] = __builtin_amdgcn_mfma_f32_16x16x32_bf16(el[cf], xh, acc[pf][cf], 0, 0, 0);
                }
            }
        }
    }

    const int k0 = kt << 7;
#pragma unroll
    for (int cf = 0; cf < 4; ++cf) {
        const int kb = k0 + (wc << 6) + (cf << 4) + (l4 << 2);
        const float4v ev = *(const float4v*)(esq + kb);
#pragma unroll
        for (int pf = 0; pf < 4; ++pf) {
            const int slotl = (wr << 6) + (pf << 4) + l15;
            const int slotg = p0 + slotl;
            if (slotg < nflag) {
                const float th = thresh_s[slotl];
#pragma unroll
                for (int r = 0; r < 4; ++r) {
                    const float s = fmaf(-2.0f, acc[pf][cf][r], ev[r]);
                    if (s <= th) {
                        int pos = atomicAdd(ccount, 1);
                        if (pos < MAXCAND) cand[pos] = ((u32)slotg << 10) | (u32)(kb + r);
                    }
                }
            }
        }
    }
}

// ---------------------------------------------------------------------------
// Exact np rescore: one thread per candidate (unchanged).
// ---------------------------------------------------------------------------
__global__ __launch_bounds__(256) void vq_cand_np(const float* __restrict__ xg,
                                                  const float* __restrict__ emb,
                                                  const float* __restrict__ esq,
                                                  const float* __restrict__ xsq_arr,
                                                  const u32* __restrict__ cand,
                                                  const int* __restrict__ ccount,
                                                  u64* __restrict__ best_arr) {
    const int ncand = min(*ccount, MAXCAND);
    const int id = blockIdx.x * 256 + threadIdx.x;
    if (id >= ncand) return;
    const u32 v = cand[id];
    const int slot = (int)(v >> 10);
    const int k = (int)(v & 1023u);
    const float cr = np_einsum_dot_256(xg + (size_t)slot * C_, emb + (size_t)k * C_);
    const float d2 = fadd_x(fsub_x(xsq_arr[slot], fmul_x(2.0f, cr)), esq[k]);
    const u64 pk = ((u64)__float_as_uint(d2) << 32) | (unsigned)k;
    atomicMin(&best_arr[slot], pk);
}

__global__ __launch_bounds__(256) void finalize_kernel(const u64* __restrict__ best_arr,
                                                       const int* __restrict__ plist,
                                                       const int* __restrict__ pcount,
                                                       int* __restrict__ idx_arr) {
    const int nflag = min(*pcount, MAXFLAG);
    const int s = blockIdx.x * 256 + threadIdx.x;
    if (s >= nflag) return;
    idx_arr[plist[s]] = (int)(best_arr[s] & 0xffffffffu);
}

// ---------------------------------------------------------------------------
// gather + STE: out = fl(fl(q - x) + x). Runs LAST. v2: float4-vectorized
// write phase (px0 16B-aligned; per-element STE arithmetic identical and in
// the same order; qs reads <=2-way bank-aliased = free).
// ---------------------------------------------------------------------------
__global__ __launch_bounds__(256) void gather_kernel(const float* __restrict__ x,
                                                     const float* __restrict__ emb,
                                                     const int* __restrict__ idx_arr,
                                                     float* __restrict__ out) {
    __shared__ int idx_s[128];
    __shared__ float qs[32][257];
    const int tid = threadIdx.x;
    const int blk = blockIdx.x;
    const int b   = blk >> 3;
    const int hw0 = (blk & 7) << 7;
    if (tid < 128) idx_s[tid] = idx_arr[blk * 128 + tid];
    __syncthreads();
    for (int ch = 0; ch < 4; ++ch) {
        const int p0c = ch << 5;
#pragma unroll 8
        for (int r = 0; r < 32; ++r)
            qs[r][tid] = emb[(size_t)idx_s[p0c + r] * C_ + tid];
        __syncthreads();
#pragma unroll
        for (int i = 0; i < 8; ++i) {
            const int lin = (i << 8) + tid;     // 0..2047
            const int c = lin >> 3;
            const int px0 = (lin & 7) << 2;
            const size_t o = ((size_t)b * C_ + c) * HW_ + hw0 + p0c + px0;
            const float4 xv = *(const float4*)(x + o);
            float4 ov;
            ov.x = fadd_x(fsub_x(qs[px0 + 0][c], xv.x), xv.x);
            ov.y = fadd_x(fsub_x(qs[px0 + 1][c], xv.y), xv.y);
            ov.z = fadd_x(fsub_x(qs[px0 + 2][c], xv.z), xv.z);
            ov.w = fadd_x(fsub_x(qs[px0 + 3][c], xv.w), xv.w);
            *(float4*)(out + o) = ov;
        }
        __syncthreads();
    }
}

extern "C" void kernel_launch(void* const* d_in, const int* in_sizes, int n_in,
                              void* d_out, int out_size, void* d_ws, size_t ws_size,
                              hipStream_t stream) {
    const float* x   = (const float*)d_in[0];
    const float* emb = (const float*)d_in[1];
    float* out = (float*)d_out;
    char* ws = (char*)d_ws;

    float* esq     = (float*)ws;                 // 4 KB
    int*   pcount  = (int*)(ws + 4096);
    int*   ccount  = (int*)(ws + 8192);
    int*   plist   = (int*)(ws + 12288);         // 32 KB
    float* m1_arr  = (float*)(ws + 65536);       // 256 KB
    int*   idx_arr = (int*)(ws + 327680);        // 256 KB
    float* xsq_arr = (float*)(ws + 589824);      // 32 KB
    u64*   best_arr= (u64*)(ws + 622592);        // 64 KB
    u32*   cand    = (u32*)(ws + 688128);        // 256 KB
    u16*   et_hi   = (u16*)(ws + 983040);        // 512 KB (tiled layout)
    u16*   et_lo   = (u16*)(ws + 1507328);       // 512 KB (base ends ~2 MB)

    // Rescue scratch lives in the out buffer (free until gather runs last).
    float* xg      = (float*)d_out;                           // 8 MB
    u16*   xgt_hi  = (u16*)((char*)d_out + (8u << 20));       // 4 MB
    u16*   xgt_lo  = (u16*)((char*)d_out + (12u << 20));      // 4 MB

    prep_e_kernel<<<K_ / 32, 256, 0, stream>>>(emb, esq, et_hi, et_lo, pcount, ccount);
    vq_main_mfma<<<NPIX / 64, 512, 0, stream>>>(x, et_hi, et_lo, esq,
                                                idx_arr, m1_arr, plist, pcount);
    gather_x_kernel<<<MAXFLAG / 8, 256, 0, stream>>>(x, plist, pcount, xg, xsq_arr,
                                                     best_arr, xgt_hi, xgt_lo);
    vq_scan_mfma<<<(MAXFLAG / 128) * 8, 256, 0, stream>>>(xgt_hi, xgt_lo, et_hi, et_lo,
                                                          esq, m1_arr, plist, pcount,
                                                          cand, ccount);
    vq_cand_np<<<MAXCAND / 256, 256, 0, stream>>>(xg, emb, esq, xsq_arr, cand, ccount,
                                                  best_arr);
    finalize_kernel<<<MAXFLAG / 256, 256, 0, stream>>>(best_arr, plist, pcount, idx_arr);
    gather_kernel<<<NPIX / 128, 256, 0, stream>>>(x, emb, idx_arr, out);
}

// Round 17
// 288.884 us; speedup vs baseline: 1.2315x; 1.0337x over previous
//
#include <hip/hip_runtime.h>

#define B_    64
#define C_    256
#define HW_   1024
#define NPIX  (B_ * HW_)
#define K_    1024
#define TAU_FLAG    2.0e-4f
#define CAND_MARGIN 2.2e-4f
#define MAXFLAG     8192
#define MAXCAND     65536

typedef unsigned short u16;
typedef unsigned int   u32;
typedef unsigned long long u64;
typedef __attribute__((ext_vector_type(8))) __bf16 bf16x8v;
typedef __attribute__((ext_vector_type(4))) float  float4v;
typedef __attribute__((address_space(1))) void gvoid;
typedef __attribute__((address_space(3))) void lvoid;

// Rounding barriers: force a separately-rounded f32 mul/add/sub (defeat
// -ffp-contract=fast fusion and any reassociation across the boundary).
__device__ __forceinline__ float fmul_x(float a, float b) { float p = a * b; asm volatile("" : "+v"(p)); return p; }
__device__ __forceinline__ float fadd_x(float a, float b) { float s = a + b; asm volatile("" : "+v"(s)); return s; }
__device__ __forceinline__ float fsub_x(float a, float b) { float s = a - b; asm volatile("" : "+v"(s)); return s; }

// f32 -> bf16 round-to-nearest-even (finite inputs only), and back.
__device__ __forceinline__ u16 bf16_rne(float f) {
    u32 u = __float_as_uint(f);
    u32 r = u + 0x7FFFu + ((u >> 16) & 1u);
    return (u16)(r >> 16);
}
__device__ __forceinline__ float bf16_to_f(u16 h) { return __uint_as_float(((u32)h) << 16); }

__device__ __forceinline__ uint4 pack8(const u16* h) {
    return make_uint4((u32)h[0] | ((u32)h[1] << 16), (u32)h[2] | ((u32)h[3] << 16),
                      (u32)h[4] | ((u32)h[5] << 16), (u32)h[6] | ((u32)h[7] << 16));
}

// ---------------------------------------------------------------------------
// numpy pairwise sum replica for 256 contiguous squares (unchanged).
// ---------------------------------------------------------------------------
__device__ __forceinline__ float np_sumsq_256(const float* __restrict__ a) {
    float half[2];
#pragma unroll
    for (int h = 0; h < 2; ++h) {
        const float* p = a + h * 128;
        float r[8];
#pragma unroll
        for (int j = 0; j < 8; ++j) r[j] = fmul_x(p[j], p[j]);
        for (int i = 8; i < 128; i += 8)
#pragma unroll
            for (int j = 0; j < 8; ++j) r[j] = fadd_x(r[j], fmul_x(p[i + j], p[i + j]));
        half[h] = fadd_x(fadd_x(fadd_x(r[0], r[1]), fadd_x(r[2], r[3])),
                         fadd_x(fadd_x(r[4], r[5]), fadd_x(r[6], r[7])));
    }
    return fadd_x(half[0], half[1]);
}

// ---------------------------------------------------------------------------
// numpy einsum f32 dot replica (unchanged).
// ---------------------------------------------------------------------------
__device__ float np_einsum_dot_256(const float* __restrict__ xr,
                                   const float* __restrict__ er) {
    float acc0 = 0.f, acc1 = 0.f, acc2 = 0.f, acc3 = 0.f;
    for (int blk = 0; blk < 256; blk += 16) {
#pragma unroll
        for (int sub = 3; sub >= 0; --sub) {
            const int base = blk + sub * 4;
            acc0 = fadd_x(acc0, fmul_x(xr[base + 0], er[base + 0]));
            acc1 = fadd_x(acc1, fmul_x(xr[base + 1], er[base + 1]));
            acc2 = fadd_x(acc2, fmul_x(xr[base + 2], er[base + 2]));
            acc3 = fadd_x(acc3, fmul_x(xr[base + 3], er[base + 3]));
        }
    }
    return fadd_x(fadd_x(acc0, acc2), fadd_x(acc1, acc3));
}

// ---------------------------------------------------------------------------
// prep_e v2: zero counters + emb -> hi/lo bf16 staged tiles (verbatim) +
// esq via the PARALLEL 16-chain numpy-pairwise tree (the exact decomposition
// validated bit-identical in gather_x since round 5): 2 passes x (32 rows x
// 8 chains) on 256 threads, then the same combine tree on 32 threads.
// ---------------------------------------------------------------------------
__global__ __launch_bounds__(256) void prep_e_kernel(const float* __restrict__ emb,
                                                     float* __restrict__ esq,
                                                     u16* __restrict__ et_hi,
                                                     u16* __restrict__ et_lo,
                                                     int* pcount, int* ccount) {
    __shared__ float rsum[32][16];
    const int tid = threadIdx.x;
    if (blockIdx.x == 0 && tid == 0) { *pcount = 0; *ccount = 0; }
    const int k  = (blockIdx.x << 5) + (tid & 31);
    const int cg = tid >> 5;
    const int kb = k >> 7;
    const int kr = k & 127;
#pragma unroll
    for (int ct = 0; ct < 4; ++ct) {
        const int c = (ct << 6) + (cg << 3);
        const float* src = emb + (size_t)k * C_ + c;
        u16 h[8], l[8];
#pragma unroll
        for (int i = 0; i < 8; ++i) {
            const float f = src[i];
            h[i] = bf16_rne(f);
            l[i] = bf16_rne(f - bf16_to_f(h[i]));
        }
        const size_t off = ((size_t)((kb << 2) + ct) << 13) + (cg << 10) + (kr << 3);
        *(uint4*)(et_hi + off) = pack8(h);
        *(uint4*)(et_lo + off) = pack8(l);
    }
    // parallel esq: chains identical to np_sumsq_256's accumulators
#pragma unroll
    for (int h = 0; h < 2; ++h) {
        const int row = tid >> 3, j = tid & 7;
        const float* q = emb + (size_t)((blockIdx.x << 5) + row) * C_ + h * 128;
        float r = fmul_x(q[j], q[j]);
        for (int i = 8; i < 128; i += 8) r = fadd_x(r, fmul_x(q[i + j], q[i + j]));
        rsum[row][h * 8 + j] = r;
    }
    __syncthreads();
    if (tid < 32) {
        const float* r0 = &rsum[tid][0];
        const float h0 = fadd_x(fadd_x(fadd_x(r0[0], r0[1]), fadd_x(r0[2], r0[3])),
                                fadd_x(fadd_x(r0[4], r0[5]), fadd_x(r0[6], r0[7])));
        const float h1 = fadd_x(fadd_x(fadd_x(r0[8], r0[9]), fadd_x(r0[10], r0[11])),
                                fadd_x(fadd_x(r0[12], r0[13]), fadd_x(r0[14], r0[15])));
        esq[(blockIdx.x << 5) + tid] = fadd_x(h0, h1);
    }
}

// ---------------------------------------------------------------------------
// MFMA bf16x3 scoring + top-2 + flag. Round-14 kernel (best measured) +
// T5 s_setprio around the MFMA cluster (2 independent blocks/CU provide the
// wave-role diversity setprio needs). Scores bitwise identical.
// 512 threads, 64 px x 1024 codes; LDS 80KB; 2 blocks/CU.
// ---------------------------------------------------------------------------
__global__ __launch_bounds__(512, 4) void vq_main_mfma(const float* __restrict__ x,
                                                       const u16* __restrict__ et_hi,
                                                       const u16* __restrict__ et_lo,
                                                       const float* __restrict__ esq,
                                                       int* __restrict__ idx_arr,
                                                       float* __restrict__ m1_arr,
                                                       int* __restrict__ plist,
                                                       int* __restrict__ pcount) {
    __shared__ __align__(16) char smem[81920];
    // XH [ct4][cg8][row64][8] @0; XL @32768; E / raw-f32 scratch @65536 (16KB)
    float* r_m1 = (float*)(smem + 65536);   // aliases E after the k-loop
    float* r_m2 = (float*)(smem + 69888);
    int*   r_i1 = (int*)(smem + 74240);

    const int tid  = threadIdx.x;
    const int lane = tid & 63;
    const int wid  = tid >> 6;        // 0..7
    const int wr   = wid >> 2;        // 0..1 (pixel half)
    const int wc   = wid & 3;         // 0..3 (code quarter)
    const int l15 = lane & 15, l4 = lane >> 4;
    // bijective XCD swizzle: consecutive-on-XCD blocks share the E stream
    const int bid = blockIdx.x;
    const int swz = ((bid & 7) << 7) + (bid >> 3);
    const int p0 = swz * 64;
    const int b   = p0 >> 10;
    const int hw0 = p0 & 1023;

    // ---- fused cvt_x prologue: build XH/XL from f32 x (4 ct phases) ----
    for (int ct = 0; ct < 4; ++ct) {
#pragma unroll
        for (int r = 0; r < 2; ++r) {
            const int task = (r << 9) + tid;        // 0..1023
            const int cl = task >> 4, seg = task & 15;
            const float4 v = *(const float4*)(x + ((size_t)(b * C_ + (ct << 6) + cl)) * HW_ +
                                              hw0 + (seg << 2));
            *(float4*)(smem + 65536 + (cl << 8) + (seg << 4)) = v;
        }
        __syncthreads();
        {
            const int cg = tid >> 6, px = tid & 63;
            u16 h[8], l[8];
#pragma unroll
            for (int i = 0; i < 8; ++i) {
                const float f = *(const float*)(smem + 65536 + (((cg << 3) + i) << 8) + (px << 2));
                h[i] = bf16_rne(f);
                l[i] = bf16_rne(f - bf16_to_f(h[i]));
            }
            *(uint4*)(smem + (ct << 13) + (cg << 10) + (px << 4)) = pack8(h);
            *(uint4*)(smem + 32768 + (ct << 13) + (cg << 10) + (px << 4)) = pack8(l);
        }
        __syncthreads();
    }

    float m1[2], m2[2]; int i1[2];
#pragma unroll
    for (int i = 0; i < 2; ++i) { m1[i] = 3.0e38f; m2[i] = 3.0e38f; i1[i] = 0; }

    for (int kt = 0; kt < 8; ++kt) {
        float4v acc[2][2];
        const float4v zero4 = {0.f, 0.f, 0.f, 0.f};
#pragma unroll
        for (int pf = 0; pf < 2; ++pf)
#pragma unroll
            for (int cf = 0; cf < 2; ++cf) acc[pf][cf] = zero4;

        for (int kg = 0; kg < 8; ++kg) {    // 32-channel steps, ascending
            __syncthreads();                // E free (prev step consumed / prologue done)
            {   // stage E: 8KB hi + 8KB lo, 2 loads/wave
                const size_t ch = (((size_t)((kt << 2) + (kg >> 1))) << 14) + ((size_t)(kg & 1) << 13);
                __builtin_amdgcn_global_load_lds(
                    (gvoid*)((const char*)et_hi + ch + (wid << 10) + (lane << 4)),
                    (lvoid*)(smem + 65536 + (wid << 10)), 16, 0, 0);
                __builtin_amdgcn_global_load_lds(
                    (gvoid*)((const char*)et_lo + ch + (wid << 10) + (lane << 4)),
                    (lvoid*)(smem + 65536 + 8192 + (wid << 10)), 16, 0, 0);
            }
            __syncthreads();                // E landed (vmcnt drained by all waves)

            bf16x8v eh[2], el[2];
#pragma unroll
            for (int cf = 0; cf < 2; ++cf) {
                const int eo = 65536 + (l4 << 11) + (((wc << 5) + (cf << 4) + l15) << 4);
                eh[cf] = *(const bf16x8v*)(smem + eo);
                el[cf] = *(const bf16x8v*)(smem + 8192 + eo);
            }
            const int ct = kg >> 1;
            const int cg = ((kg & 1) << 2) + l4;
            __builtin_amdgcn_s_setprio(1);
#pragma unroll
            for (int pf = 0; pf < 2; ++pf) {
                const int xo = (ct << 13) + (cg << 10) + (((wr << 5) + (pf << 4) + l15) << 4);
                const bf16x8v xh = *(const bf16x8v*)(smem + xo);
                const bf16x8v xl = *(const bf16x8v*)(smem + 32768 + xo);
#pragma unroll
                for (int cf = 0; cf < 2; ++cf) {
                    acc[pf][cf] = __builtin_amdgcn_mfma_f32_16x16x32_bf16(eh[cf], xh, acc[pf][cf], 0, 0, 0);
                    acc[pf][cf] = __builtin_amdgcn_mfma_f32_16x16x32_bf16(eh[cf], xl, acc[pf][cf], 0, 0, 0);
                    acc[pf][cf] = __builtin_amdgcn_mfma_f32_16x16x32_bf16(el[cf], xh, acc[pf][cf], 0, 0, 0);
                }
            }
            __builtin_amdgcn_s_setprio(0);
        }
        // top-2 update; k ascending per pixel slot (cf outer, reg inner)
        const int k0 = kt << 7;
#pragma unroll
        for (int cf = 0; cf < 2; ++cf) {
            const int kb = k0 + (wc << 5) + (cf << 4) + (l4 << 2);
            const float4v ev = *(const float4v*)(esq + kb);
#pragma unroll
            for (int pf = 0; pf < 2; ++pf) {
#pragma unroll
                for (int r = 0; r < 4; ++r) {
                    const float s = fmaf(-2.0f, acc[pf][cf][r], ev[r]);
                    const int k = kb + r;
                    if (s < m1[pf])      { m2[pf] = m1[pf]; m1[pf] = s; i1[pf] = k; }
                    else if (s < m2[pf]) { m2[pf] = s; }
                }
            }
        }
    }

    __syncthreads();    // all E reads done; alias reduction arrays
#pragma unroll
    for (int pf = 0; pf < 2; ++pf) {
        const int p = (wr << 5) + (pf << 4) + l15;   // 0..63
        const int slot = (wc << 2) + l4;             // 0..15
        r_m1[p * 17 + slot] = m1[pf]; r_m2[p * 17 + slot] = m2[pf]; r_i1[p * 17 + slot] = i1[pf];
    }
    __syncthreads();
    if (tid < 64) {
        const int p = tid;
        float M1 = r_m1[p * 17 + 0], M2 = r_m2[p * 17 + 0];
        int   I1 = r_i1[p * 17 + 0];
        for (int t = 1; t < 16; ++t) {
            const float a1 = r_m1[p * 17 + t], a2 = r_m2[p * 17 + t];
            const int   ai = r_i1[p * 17 + t];
            if (a1 < M1 || (a1 == M1 && ai < I1)) { M2 = fminf(M1, a2); M1 = a1; I1 = ai; }
            else                                  { M2 = fminf(M2, a1); }
        }
        const int pix = p0 + p;
        idx_arr[pix] = I1;
        m1_arr[pix] = M1;
        if (M2 - M1 <= TAU_FLAG) {
            int pos = atomicAdd(pcount, 1);
            if (pos < MAXFLAG) plist[pos] = pix;
        }
    }
}

// ---------------------------------------------------------------------------
// gather_x v2 (unchanged): 8 flagged slots per block; emits xg, xsq,
// best-init and the bf16 xgt tiles directly.
// ---------------------------------------------------------------------------
__global__ __launch_bounds__(256) void gather_x_kernel(const float* __restrict__ x,
                                                       const int* __restrict__ plist,
                                                       const int* __restrict__ pcount,
                                                       float* __restrict__ xg,
                                                       float* __restrict__ xsq_arr,
                                                       u64* __restrict__ best_arr,
                                                       u16* __restrict__ xgt_hi,
                                                       u16* __restrict__ xgt_lo) {
    __shared__ float xs[8][264];
    __shared__ float rsum[8][16];
    __shared__ int pix_s[8];
    const int nflag = min(*pcount, MAXFLAG);
    const int sbase = blockIdx.x << 3;
    if (sbase >= nflag) return;
    const int nact = min(8, nflag - sbase);
    const int tid = threadIdx.x;

    if (tid < 8) pix_s[tid] = (tid < nact) ? plist[sbase + tid] : plist[sbase];
    __syncthreads();
#pragma unroll
    for (int p = 0; p < 8; ++p) {       // 8 independent scattered loads in flight
        const int pix = pix_s[p];
        const int b = pix >> 10, hw = pix & 1023;
        const float v = x[((size_t)(b * C_ + tid)) * HW_ + hw];
        xs[p][tid] = v;
        if (p < nact) xg[(size_t)(sbase + p) * C_ + tid] = v;
    }
    __syncthreads();
    if (tid < 128) {                    // 8 slots x 16 chains, exact np tree
        const int p = tid >> 4, h = (tid >> 3) & 1, j = tid & 7;
        const float* q = &xs[p][h * 128];
        float r = fmul_x(q[j], q[j]);
        for (int i = 8; i < 128; i += 8) r = fadd_x(r, fmul_x(q[i + j], q[i + j]));
        rsum[p][h * 8 + j] = r;
    }
    __syncthreads();
    if (tid < 8 && tid < nact) {
        const float* r0 = &rsum[tid][0];
        const float h0 = fadd_x(fadd_x(fadd_x(r0[0], r0[1]), fadd_x(r0[2], r0[3])),
                                fadd_x(fadd_x(r0[4], r0[5]), fadd_x(r0[6], r0[7])));
        const float h1 = fadd_x(fadd_x(fadd_x(r0[8], r0[9]), fadd_x(r0[10], r0[11])),
                                fadd_x(fadd_x(r0[12], r0[13]), fadd_x(r0[14], r0[15])));
        xsq_arr[sbase + tid] = fadd_x(h0, h1);
        best_arr[sbase + tid] = ~0ull;
    }
    // emit bf16 staged tiles (identical values & layout)
    {
        const int p  = tid >> 5;            // 0..7
        const int ct = (tid >> 3) & 3;      // 0..3
        const int cg = tid & 7;             // 0..7
        if (p < nact) {
            const int s  = sbase + p;
            const int sb = s >> 7;
            const int sr = s & 127;
            const int c = (ct << 6) + (cg << 3);
            u16 h[8], l[8];
#pragma unroll
            for (int i = 0; i < 8; ++i) {
                const float f = xs[p][c + i];
                h[i] = bf16_rne(f);
                l[i] = bf16_rne(f - bf16_to_f(h[i]));
            }
            const size_t off = ((size_t)((sb << 2) + ct) << 13) + (cg << 10) + (sr << 3);
            *(uint4*)(xgt_hi + off) = pack8(h);
            *(uint4*)(xgt_lo + off) = pack8(l);
        }
    }
}

// ---------------------------------------------------------------------------
// MFMA scan of flagged slots (unchanged): 128 slots x 128 codes per block;
// candidates appended to a global list.
// ---------------------------------------------------------------------------
__global__ __launch_bounds__(256) void vq_scan_mfma(const u16* __restrict__ xgt_hi,
                                                    const u16* __restrict__ xgt_lo,
                                                    const u16* __restrict__ et_hi,
                                                    const u16* __restrict__ et_lo,
                                                    const float* __restrict__ esq,
                                                    const float* __restrict__ m1_arr,
                                                    const int* __restrict__ plist,
                                                    const int* __restrict__ pcount,
                                                    u32* __restrict__ cand,
                                                    int* __restrict__ ccount) {
    __shared__ __align__(16) u16 xsb_hi[8192], xsb_lo[8192], esb_hi[8192], esb_lo[8192];
    __shared__ float thresh_s[128];

    const int nflag = min(*pcount, MAXFLAG);
    const int st = blockIdx.x >> 3;     // slot tile
    const int kt = blockIdx.x & 7;      // code tile
    const int p0 = st << 7;
    if (p0 >= nflag) return;
    const int tid = threadIdx.x;
    if (tid < 128) {
        const int s = p0 + tid;
        thresh_s[tid] = (s < nflag) ? (m1_arr[plist[s]] + CAND_MARGIN) : -3.0e38f;
    }

    const int lane = tid & 63;
    const int wid  = tid >> 6;
    const int wr = wid >> 1, wc = wid & 1;
    const int l15 = lane & 15, l4 = lane >> 4;

    const char* xhb = (const char*)xgt_hi + ((size_t)st << 16);
    const char* xlb = (const char*)xgt_lo + ((size_t)st << 16);
    const char* ehb = (const char*)et_hi + ((size_t)(kt << 2) << 14);
    const char* elb = (const char*)et_lo + ((size_t)(kt << 2) << 14);

    float4v acc[4][4];
    const float4v zero4 = {0.f, 0.f, 0.f, 0.f};
#pragma unroll
    for (int pf = 0; pf < 4; ++pf)
#pragma unroll
        for (int cf = 0; cf < 4; ++cf) acc[pf][cf] = zero4;

    for (int ct = 0; ct < 4; ++ct) {
        const int coff = ct << 14;
        __syncthreads();
#pragma unroll
        for (int i = 0; i < 4; ++i) {
            const int off = (((i << 2) + wid) << 10);
            const int src = off + (lane << 4);
            __builtin_amdgcn_global_load_lds((gvoid*)(xhb + coff + src),
                (lvoid*)((char*)xsb_hi + off), 16, 0, 0);
            __builtin_amdgcn_global_load_lds((gvoid*)(xlb + coff + src),
                (lvoid*)((char*)xsb_lo + off), 16, 0, 0);
            __builtin_amdgcn_global_load_lds((gvoid*)(ehb + coff + src),
                (lvoid*)((char*)esb_hi + off), 16, 0, 0);
            __builtin_amdgcn_global_load_lds((gvoid*)(elb + coff + src),
                (lvoid*)((char*)esb_lo + off), 16, 0, 0);
        }
        __syncthreads();
#pragma unroll
        for (int ks = 0; ks < 2; ++ks) {
            const int cgb = (ks << 2) + l4;
            const int ebase = (cgb << 7) + (wc << 6) + l15;
            const int xbase = (cgb << 7) + (wr << 6) + l15;
            bf16x8v eh[4], el[4];
#pragma unroll
            for (int cf = 0; cf < 4; ++cf) {
                const int eo = (ebase + (cf << 4)) << 3;
                eh[cf] = *(const bf16x8v*)(esb_hi + eo);
                el[cf] = *(const bf16x8v*)(esb_lo + eo);
            }
#pragma unroll
            for (int pf = 0; pf < 4; ++pf) {
                const int xo = (xbase + (pf << 4)) << 3;
                const bf16x8v xh = *(const bf16x8v*)(xsb_hi + xo);
                const bf16x8v xl = *(const bf16x8v*)(xsb_lo + xo);
#pragma unroll
                for (int cf = 0; cf < 4; ++cf) {
                    acc[pf][cf] = __builtin_amdgcn_mfma_f32_16x16x32_bf16(eh[cf], xh, acc[pf][cf], 0, 0, 0);
                    acc[pf][cf] = __builtin_amdgcn_mfma_f32_16x16x32_bf16(eh[cf], xl, acc[pf][cf], 0, 0, 0);
                    acc[pf][cf] = __builtin_amdgcn_mfma_f32_16x16x32_bf16(el[cf], xh, acc[pf][cf], 0, 0, 0);
                }
            }
        }
    }

    const int k0 = kt << 7;
#pragma unroll
    for (int cf = 0; cf < 4; ++cf) {
        const int kb = k0 + (wc << 6) + (cf << 4) + (l4 << 2);
        const float4v ev = *(const float4v*)(esq + kb);
#pragma unroll
        for (int pf = 0; pf < 4; ++pf) {
            const int slotl = (wr << 6) + (pf << 4) + l15;
            const int slotg = p0 + slotl;
            if (slotg < nflag) {
                const float th = thresh_s[slotl];
#pragma unroll
                for (int r = 0; r < 4; ++r) {
                    const float s = fmaf(-2.0f, acc[pf][cf][r], ev[r]);
                    if (s <= th) {
                        int pos = atomicAdd(ccount, 1);
                        if (pos < MAXCAND) cand[pos] = ((u32)slotg << 10) | (u32)(kb + r);
                    }
                }
            }
        }
    }
}

// ---------------------------------------------------------------------------
// Exact np rescore: one thread per candidate (unchanged).
// ---------------------------------------------------------------------------
__global__ __launch_bounds__(256) void vq_cand_np(const float* __restrict__ xg,
                                                  const float* __restrict__ emb,
                                                  const float* __restrict__ esq,
                                                  const float* __restrict__ xsq_arr,
                                                  const u32* __restrict__ cand,
                                                  const int* __restrict__ ccount,
                                                  u64* __restrict__ best_arr) {
    const int ncand = min(*ccount, MAXCAND);
    const int id = blockIdx.x * 256 + threadIdx.x;
    if (id >= ncand) return;
    const u32 v = cand[id];
    const int slot = (int)(v >> 10);
    const int k = (int)(v & 1023u);
    const float cr = np_einsum_dot_256(xg + (size_t)slot * C_, emb + (size_t)k * C_);
    const float d2 = fadd_x(fsub_x(xsq_arr[slot], fmul_x(2.0f, cr)), esq[k]);
    const u64 pk = ((u64)__float_as_uint(d2) << 32) | (unsigned)k;
    atomicMin(&best_arr[slot], pk);
}

__global__ __launch_bounds__(256) void finalize_kernel(const u64* __restrict__ best_arr,
                                                       const int* __restrict__ plist,
                                                       const int* __restrict__ pcount,
                                                       int* __restrict__ idx_arr) {
    const int nflag = min(*pcount, MAXFLAG);
    const int s = blockIdx.x * 256 + threadIdx.x;
    if (s >= nflag) return;
    idx_arr[plist[s]] = (int)(best_arr[s] & 0xffffffffu);
}

// ---------------------------------------------------------------------------
// gather + STE: out = fl(fl(q - x) + x). Runs LAST. v2: float4-vectorized
// write phase (px0 16B-aligned; per-element STE arithmetic identical and in
// the same order; qs reads <=2-way bank-aliased = free).
// ---------------------------------------------------------------------------
__global__ __launch_bounds__(256) void gather_kernel(const float* __restrict__ x,
                                                     const float* __restrict__ emb,
                                                     const int* __restrict__ idx_arr,
                                                     float* __restrict__ out) {
    __shared__ int idx_s[128];
    __shared__ float qs[32][257];
    const int tid = threadIdx.x;
    const int blk = blockIdx.x;
    const int b   = blk >> 3;
    const int hw0 = (blk & 7) << 7;
    if (tid < 128) idx_s[tid] = idx_arr[blk * 128 + tid];
    __syncthreads();
    for (int ch = 0; ch < 4; ++ch) {
        const int p0c = ch << 5;
#pragma unroll 8
        for (int r = 0; r < 32; ++r)
            qs[r][tid] = emb[(size_t)idx_s[p0c + r] * C_ + tid];
        __syncthreads();
#pragma unroll
        for (int i = 0; i < 8; ++i) {
            const int lin = (i << 8) + tid;     // 0..2047
            const int c = lin >> 3;
            const int px0 = (lin & 7) << 2;
            const size_t o = ((size_t)b * C_ + c) * HW_ + hw0 + p0c + px0;
            const float4 xv = *(const float4*)(x + o);
            float4 ov;
            ov.x = fadd_x(fsub_x(qs[px0 + 0][c], xv.x), xv.x);
            ov.y = fadd_x(fsub_x(qs[px0 + 1][c], xv.y), xv.y);
            ov.z = fadd_x(fsub_x(qs[px0 + 2][c], xv.z), xv.z);
            ov.w = fadd_x(fsub_x(qs[px0 + 3][c], xv.w), xv.w);
            *(float4*)(out + o) = ov;
        }
        __syncthreads();
    }
}

extern "C" void kernel_launch(void* const* d_in, const int* in_sizes, int n_in,
                              void* d_out, int out_size, void* d_ws, size_t ws_size,
                              hipStream_t stream) {
    const float* x   = (const float*)d_in[0];
    const float* emb = (const float*)d_in[1];
    float* out = (float*)d_out;
    char* ws = (char*)d_ws;

    float* esq     = (float*)ws;                 // 4 KB
    int*   pcount  = (int*)(ws + 4096);
    int*   ccount  = (int*)(ws + 8192);
    int*   plist   = (int*)(ws + 12288);         // 32 KB
    float* m1_arr  = (float*)(ws + 65536);       // 256 KB
    int*   idx_arr = (int*)(ws + 327680);        // 256 KB
    float* xsq_arr = (float*)(ws + 589824);      // 32 KB
    u64*   best_arr= (u64*)(ws + 622592);        // 64 KB
    u32*   cand    = (u32*)(ws + 688128);        // 256 KB
    u16*   et_hi   = (u16*)(ws + 983040);        // 512 KB (tiled layout)
    u16*   et_lo   = (u16*)(ws + 1507328);       // 512 KB (base ends ~2 MB)

    // Rescue scratch lives in the out buffer (free until gather runs last).
    float* xg      = (float*)d_out;                           // 8 MB
    u16*   xgt_hi  = (u16*)((char*)d_out + (8u << 20));       // 4 MB
    u16*   xgt_lo  = (u16*)((char*)d_out + (12u << 20));      // 4 MB

    prep_e_kernel<<<K_ / 32, 256, 0, stream>>>(emb, esq, et_hi, et_lo, pcount, ccount);
    vq_main_mfma<<<NPIX / 64, 512, 0, stream>>>(x, et_hi, et_lo, esq,
                                                idx_arr, m1_arr, plist, pcount);
    gather_x_kernel<<<MAXFLAG / 8, 256, 0, stream>>>(x, plist, pcount, xg, xsq_arr,
                                                     best_arr, xgt_hi, xgt_lo);
    vq_scan_mfma<<<(MAXFLAG / 128) * 8, 256, 0, stream>>>(xgt_hi, xgt_lo, et_hi, et_lo,
                                                          esq, m1_arr, plist, pcount,
                                                          cand, ccount);
    vq_cand_np<<<MAXCAND / 256, 256, 0, stream>>>(xg, emb, esq, xsq_arr, cand, ccount,
                                                  best_arr);
    finalize_kernel<<<MAXFLAG / 256, 256, 0, stream>>>(best_arr, plist, pcount, idx_arr);
    gather_kernel<<<NPIX / 128, 256, 0, stream>>>(x, emb, idx_arr, out);
}

// Round 18
// 283.555 us; speedup vs baseline: 1.2546x; 1.0188x over previous
//
#include <hip/hip_runtime.h>

#define B_    64
#define C_    256
#define HW_   1024
#define NPIX  (B_ * HW_)
#define K_    1024
#define TAU_FLAG    2.0e-4f
#define CAND_MARGIN 2.2e-4f
#define MAXFLAG     8192
#define MAXCAND     65536

typedef unsigned short u16;
typedef unsigned int   u32;
typedef unsigned long long u64;
typedef __attribute__((ext_vector_type(8))) __bf16 bf16x8v;
typedef __attribute__((ext_vector_type(4))) float  float4v;
typedef __attribute__((address_space(1))) void gvoid;
typedef __attribute__((address_space(3))) void lvoid;

// Rounding barriers: force a separately-rounded f32 mul/add/sub (defeat
// -ffp-contract=fast fusion and any reassociation across the boundary).
__device__ __forceinline__ float fmul_x(float a, float b) { float p = a * b; asm volatile("" : "+v"(p)); return p; }
__device__ __forceinline__ float fadd_x(float a, float b) { float s = a + b; asm volatile("" : "+v"(s)); return s; }
__device__ __forceinline__ float fsub_x(float a, float b) { float s = a - b; asm volatile("" : "+v"(s)); return s; }

// f32 -> bf16 round-to-nearest-even (finite inputs only), and back.
__device__ __forceinline__ u16 bf16_rne(float f) {
    u32 u = __float_as_uint(f);
    u32 r = u + 0x7FFFu + ((u >> 16) & 1u);
    return (u16)(r >> 16);
}
__device__ __forceinline__ float bf16_to_f(u16 h) { return __uint_as_float(((u32)h) << 16); }

__device__ __forceinline__ uint4 pack8(const u16* h) {
    return make_uint4((u32)h[0] | ((u32)h[1] << 16), (u32)h[2] | ((u32)h[3] << 16),
                      (u32)h[4] | ((u32)h[5] << 16), (u32)h[6] | ((u32)h[7] << 16));
}

// ---------------------------------------------------------------------------
// numpy pairwise sum replica for 256 contiguous squares (unchanged).
// ---------------------------------------------------------------------------
__device__ __forceinline__ float np_sumsq_256(const float* __restrict__ a) {
    float half[2];
#pragma unroll
    for (int h = 0; h < 2; ++h) {
        const float* p = a + h * 128;
        float r[8];
#pragma unroll
        for (int j = 0; j < 8; ++j) r[j] = fmul_x(p[j], p[j]);
        for (int i = 8; i < 128; i += 8)
#pragma unroll
            for (int j = 0; j < 8; ++j) r[j] = fadd_x(r[j], fmul_x(p[i + j], p[i + j]));
        half[h] = fadd_x(fadd_x(fadd_x(r[0], r[1]), fadd_x(r[2], r[3])),
                         fadd_x(fadd_x(r[4], r[5]), fadd_x(r[6], r[7])));
    }
    return fadd_x(half[0], half[1]);
}

// ---------------------------------------------------------------------------
// numpy einsum f32 dot replica (unchanged).
// ---------------------------------------------------------------------------
__device__ float np_einsum_dot_256(const float* __restrict__ xr,
                                   const float* __restrict__ er) {
    float acc0 = 0.f, acc1 = 0.f, acc2 = 0.f, acc3 = 0.f;
    for (int blk = 0; blk < 256; blk += 16) {
#pragma unroll
        for (int sub = 3; sub >= 0; --sub) {
            const int base = blk + sub * 4;
            acc0 = fadd_x(acc0, fmul_x(xr[base + 0], er[base + 0]));
            acc1 = fadd_x(acc1, fmul_x(xr[base + 1], er[base + 1]));
            acc2 = fadd_x(acc2, fmul_x(xr[base + 2], er[base + 2]));
            acc3 = fadd_x(acc3, fmul_x(xr[base + 3], er[base + 3]));
        }
    }
    return fadd_x(fadd_x(acc0, acc2), fadd_x(acc1, acc3));
}

// ---------------------------------------------------------------------------
// prep_e v2: zero counters + emb -> hi/lo bf16 staged tiles (verbatim) +
// esq via the PARALLEL 16-chain numpy-pairwise tree (validated bit-identical
// decomposition). Grid 32 x 256.
// ---------------------------------------------------------------------------
__global__ __launch_bounds__(256) void prep_e_kernel(const float* __restrict__ emb,
                                                     float* __restrict__ esq,
                                                     u16* __restrict__ et_hi,
                                                     u16* __restrict__ et_lo,
                                                     int* pcount, int* ccount) {
    __shared__ float rsum[32][16];
    const int tid = threadIdx.x;
    if (blockIdx.x == 0 && tid == 0) { *pcount = 0; *ccount = 0; }
    const int k  = (blockIdx.x << 5) + (tid & 31);
    const int cg = tid >> 5;
    const int kb = k >> 7;
    const int kr = k & 127;
#pragma unroll
    for (int ct = 0; ct < 4; ++ct) {
        const int c = (ct << 6) + (cg << 3);
        const float* src = emb + (size_t)k * C_ + c;
        u16 h[8], l[8];
#pragma unroll
        for (int i = 0; i < 8; ++i) {
            const float f = src[i];
            h[i] = bf16_rne(f);
            l[i] = bf16_rne(f - bf16_to_f(h[i]));
        }
        const size_t off = ((size_t)((kb << 2) + ct) << 13) + (cg << 10) + (kr << 3);
        *(uint4*)(et_hi + off) = pack8(h);
        *(uint4*)(et_lo + off) = pack8(l);
    }
    // parallel esq: chains identical to np_sumsq_256's accumulators
#pragma unroll
    for (int h = 0; h < 2; ++h) {
        const int row = tid >> 3, j = tid & 7;
        const float* q = emb + (size_t)((blockIdx.x << 5) + row) * C_ + h * 128;
        float r = fmul_x(q[j], q[j]);
        for (int i = 8; i < 128; i += 8) r = fadd_x(r, fmul_x(q[i + j], q[i + j]));
        rsum[row][h * 8 + j] = r;
    }
    __syncthreads();
    if (tid < 32) {
        const float* r0 = &rsum[tid][0];
        const float h0 = fadd_x(fadd_x(fadd_x(r0[0], r0[1]), fadd_x(r0[2], r0[3])),
                                fadd_x(fadd_x(r0[4], r0[5]), fadd_x(r0[6], r0[7])));
        const float h1 = fadd_x(fadd_x(fadd_x(r0[8], r0[9]), fadd_x(r0[10], r0[11])),
                                fadd_x(fadd_x(r0[12], r0[13]), fadd_x(r0[14], r0[15])));
        esq[(blockIdx.x << 5) + tid] = fadd_x(h0, h1);
    }
}

// ---------------------------------------------------------------------------
// MFMA bf16x3 scoring + top-2 + flag. Verbatim round-16 kernel (best
// measured main: 139 us) — setprio removed (r17 A/B showed it costs ~2.5%).
// Scores bitwise identical to rounds 2-17.
// 512 threads, 64 px x 1024 codes; LDS 80KB; 2 blocks/CU.
// ---------------------------------------------------------------------------
__global__ __launch_bounds__(512, 4) void vq_main_mfma(const float* __restrict__ x,
                                                       const u16* __restrict__ et_hi,
                                                       const u16* __restrict__ et_lo,
                                                       const float* __restrict__ esq,
                                                       int* __restrict__ idx_arr,
                                                       float* __restrict__ m1_arr,
                                                       int* __restrict__ plist,
                                                       int* __restrict__ pcount) {
    __shared__ __align__(16) char smem[81920];
    // XH [ct4][cg8][row64][8] @0; XL @32768; E / raw-f32 scratch @65536 (16KB)
    float* r_m1 = (float*)(smem + 65536);   // aliases E after the k-loop
    float* r_m2 = (float*)(smem + 69888);
    int*   r_i1 = (int*)(smem + 74240);

    const int tid  = threadIdx.x;
    const int lane = tid & 63;
    const int wid  = tid >> 6;        // 0..7
    const int wr   = wid >> 2;        // 0..1 (pixel half)
    const int wc   = wid & 3;         // 0..3 (code quarter)
    const int l15 = lane & 15, l4 = lane >> 4;
    // bijective XCD swizzle: consecutive-on-XCD blocks share the E stream
    const int bid = blockIdx.x;
    const int swz = ((bid & 7) << 7) + (bid >> 3);
    const int p0 = swz * 64;
    const int b   = p0 >> 10;
    const int hw0 = p0 & 1023;

    // ---- fused cvt_x prologue: build XH/XL from f32 x (4 ct phases) ----
    for (int ct = 0; ct < 4; ++ct) {
#pragma unroll
        for (int r = 0; r < 2; ++r) {
            const int task = (r << 9) + tid;        // 0..1023
            const int cl = task >> 4, seg = task & 15;
            const float4 v = *(const float4*)(x + ((size_t)(b * C_ + (ct << 6) + cl)) * HW_ +
                                              hw0 + (seg << 2));
            *(float4*)(smem + 65536 + (cl << 8) + (seg << 4)) = v;
        }
        __syncthreads();
        {
            const int cg = tid >> 6, px = tid & 63;
            u16 h[8], l[8];
#pragma unroll
            for (int i = 0; i < 8; ++i) {
                const float f = *(const float*)(smem + 65536 + (((cg << 3) + i) << 8) + (px << 2));
                h[i] = bf16_rne(f);
                l[i] = bf16_rne(f - bf16_to_f(h[i]));
            }
            *(uint4*)(smem + (ct << 13) + (cg << 10) + (px << 4)) = pack8(h);
            *(uint4*)(smem + 32768 + (ct << 13) + (cg << 10) + (px << 4)) = pack8(l);
        }
        __syncthreads();
    }

    float m1[2], m2[2]; int i1[2];
#pragma unroll
    for (int i = 0; i < 2; ++i) { m1[i] = 3.0e38f; m2[i] = 3.0e38f; i1[i] = 0; }

    for (int kt = 0; kt < 8; ++kt) {
        float4v acc[2][2];
        const float4v zero4 = {0.f, 0.f, 0.f, 0.f};
#pragma unroll
        for (int pf = 0; pf < 2; ++pf)
#pragma unroll
            for (int cf = 0; cf < 2; ++cf) acc[pf][cf] = zero4;

        for (int kg = 0; kg < 8; ++kg) {    // 32-channel steps, ascending
            __syncthreads();                // E free (prev step consumed / prologue done)
            {   // stage E: 8KB hi + 8KB lo, 2 loads/wave
                const size_t ch = (((size_t)((kt << 2) + (kg >> 1))) << 14) + ((size_t)(kg & 1) << 13);
                __builtin_amdgcn_global_load_lds(
                    (gvoid*)((const char*)et_hi + ch + (wid << 10) + (lane << 4)),
                    (lvoid*)(smem + 65536 + (wid << 10)), 16, 0, 0);
                __builtin_amdgcn_global_load_lds(
                    (gvoid*)((const char*)et_lo + ch + (wid << 10) + (lane << 4)),
                    (lvoid*)(smem + 65536 + 8192 + (wid << 10)), 16, 0, 0);
            }
            __syncthreads();                // E landed (vmcnt drained by all waves)

            bf16x8v eh[2], el[2];
#pragma unroll
            for (int cf = 0; cf < 2; ++cf) {
                const int eo = 65536 + (l4 << 11) + (((wc << 5) + (cf << 4) + l15) << 4);
                eh[cf] = *(const bf16x8v*)(smem + eo);
                el[cf] = *(const bf16x8v*)(smem + 8192 + eo);
            }
            const int ct = kg >> 1;
            const int cg = ((kg & 1) << 2) + l4;
#pragma unroll
            for (int pf = 0; pf < 2; ++pf) {
                const int xo = (ct << 13) + (cg << 10) + (((wr << 5) + (pf << 4) + l15) << 4);
                const bf16x8v xh = *(const bf16x8v*)(smem + xo);
                const bf16x8v xl = *(const bf16x8v*)(smem + 32768 + xo);
#pragma unroll
                for (int cf = 0; cf < 2; ++cf) {
                    acc[pf][cf] = __builtin_amdgcn_mfma_f32_16x16x32_bf16(eh[cf], xh, acc[pf][cf], 0, 0, 0);
                    acc[pf][cf] = __builtin_amdgcn_mfma_f32_16x16x32_bf16(eh[cf], xl, acc[pf][cf], 0, 0, 0);
                    acc[pf][cf] = __builtin_amdgcn_mfma_f32_16x16x32_bf16(el[cf], xh, acc[pf][cf], 0, 0, 0);
                }
            }
        }
        // top-2 update; k ascending per pixel slot (cf outer, reg inner)
        const int k0 = kt << 7;
#pragma unroll
        for (int cf = 0; cf < 2; ++cf) {
            const int kb = k0 + (wc << 5) + (cf << 4) + (l4 << 2);
            const float4v ev = *(const float4v*)(esq + kb);
#pragma unroll
            for (int pf = 0; pf < 2; ++pf) {
#pragma unroll
                for (int r = 0; r < 4; ++r) {
                    const float s = fmaf(-2.0f, acc[pf][cf][r], ev[r]);
                    const int k = kb + r;
                    if (s < m1[pf])      { m2[pf] = m1[pf]; m1[pf] = s; i1[pf] = k; }
                    else if (s < m2[pf]) { m2[pf] = s; }
                }
            }
        }
    }

    __syncthreads();    // all E reads done; alias reduction arrays
#pragma unroll
    for (int pf = 0; pf < 2; ++pf) {
        const int p = (wr << 5) + (pf << 4) + l15;   // 0..63
        const int slot = (wc << 2) + l4;             // 0..15
        r_m1[p * 17 + slot] = m1[pf]; r_m2[p * 17 + slot] = m2[pf]; r_i1[p * 17 + slot] = i1[pf];
    }
    __syncthreads();
    if (tid < 64) {
        const int p = tid;
        float M1 = r_m1[p * 17 + 0], M2 = r_m2[p * 17 + 0];
        int   I1 = r_i1[p * 17 + 0];
        for (int t = 1; t < 16; ++t) {
            const float a1 = r_m1[p * 17 + t], a2 = r_m2[p * 17 + t];
            const int   ai = r_i1[p * 17 + t];
            if (a1 < M1 || (a1 == M1 && ai < I1)) { M2 = fminf(M1, a2); M1 = a1; I1 = ai; }
            else                                  { M2 = fminf(M2, a1); }
        }
        const int pix = p0 + p;
        idx_arr[pix] = I1;
        m1_arr[pix] = M1;
        if (M2 - M1 <= TAU_FLAG) {
            int pos = atomicAdd(pcount, 1);
            if (pos < MAXFLAG) plist[pos] = pix;
        }
    }
}

// ---------------------------------------------------------------------------
// gather_x v2 (unchanged): 8 flagged slots per block; emits xg, xsq,
// best-init and the bf16 xgt tiles directly.
// ---------------------------------------------------------------------------
__global__ __launch_bounds__(256) void gather_x_kernel(const float* __restrict__ x,
                                                       const int* __restrict__ plist,
                                                       const int* __restrict__ pcount,
                                                       float* __restrict__ xg,
                                                       float* __restrict__ xsq_arr,
                                                       u64* __restrict__ best_arr,
                                                       u16* __restrict__ xgt_hi,
                                                       u16* __restrict__ xgt_lo) {
    __shared__ float xs[8][264];
    __shared__ float rsum[8][16];
    __shared__ int pix_s[8];
    const int nflag = min(*pcount, MAXFLAG);
    const int sbase = blockIdx.x << 3;
    if (sbase >= nflag) return;
    const int nact = min(8, nflag - sbase);
    const int tid = threadIdx.x;

    if (tid < 8) pix_s[tid] = (tid < nact) ? plist[sbase + tid] : plist[sbase];
    __syncthreads();
#pragma unroll
    for (int p = 0; p < 8; ++p) {       // 8 independent scattered loads in flight
        const int pix = pix_s[p];
        const int b = pix >> 10, hw = pix & 1023;
        const float v = x[((size_t)(b * C_ + tid)) * HW_ + hw];
        xs[p][tid] = v;
        if (p < nact) xg[(size_t)(sbase + p) * C_ + tid] = v;
    }
    __syncthreads();
    if (tid < 128) {                    // 8 slots x 16 chains, exact np tree
        const int p = tid >> 4, h = (tid >> 3) & 1, j = tid & 7;
        const float* q = &xs[p][h * 128];
        float r = fmul_x(q[j], q[j]);
        for (int i = 8; i < 128; i += 8) r = fadd_x(r, fmul_x(q[i + j], q[i + j]));
        rsum[p][h * 8 + j] = r;
    }
    __syncthreads();
    if (tid < 8 && tid < nact) {
        const float* r0 = &rsum[tid][0];
        const float h0 = fadd_x(fadd_x(fadd_x(r0[0], r0[1]), fadd_x(r0[2], r0[3])),
                                fadd_x(fadd_x(r0[4], r0[5]), fadd_x(r0[6], r0[7])));
        const float h1 = fadd_x(fadd_x(fadd_x(r0[8], r0[9]), fadd_x(r0[10], r0[11])),
                                fadd_x(fadd_x(r0[12], r0[13]), fadd_x(r0[14], r0[15])));
        xsq_arr[sbase + tid] = fadd_x(h0, h1);
        best_arr[sbase + tid] = ~0ull;
    }
    // emit bf16 staged tiles (identical values & layout)
    {
        const int p  = tid >> 5;            // 0..7
        const int ct = (tid >> 3) & 3;      // 0..3
        const int cg = tid & 7;             // 0..7
        if (p < nact) {
            const int s  = sbase + p;
            const int sb = s >> 7;
            const int sr = s & 127;
            const int c = (ct << 6) + (cg << 3);
            u16 h[8], l[8];
#pragma unroll
            for (int i = 0; i < 8; ++i) {
                const float f = xs[p][c + i];
                h[i] = bf16_rne(f);
                l[i] = bf16_rne(f - bf16_to_f(h[i]));
            }
            const size_t off = ((size_t)((sb << 2) + ct) << 13) + (cg << 10) + (sr << 3);
            *(uint4*)(xgt_hi + off) = pack8(h);
            *(uint4*)(xgt_lo + off) = pack8(l);
        }
    }
}

// ---------------------------------------------------------------------------
// MFMA scan of flagged slots (unchanged): 128 slots x 128 codes per block;
// candidates appended to a global list.
// ---------------------------------------------------------------------------
__global__ __launch_bounds__(256) void vq_scan_mfma(const u16* __restrict__ xgt_hi,
                                                    const u16* __restrict__ xgt_lo,
                                                    const u16* __restrict__ et_hi,
                                                    const u16* __restrict__ et_lo,
                                                    const float* __restrict__ esq,
                                                    const float* __restrict__ m1_arr,
                                                    const int* __restrict__ plist,
                                                    const int* __restrict__ pcount,
                                                    u32* __restrict__ cand,
                                                    int* __restrict__ ccount) {
    __shared__ __align__(16) u16 xsb_hi[8192], xsb_lo[8192], esb_hi[8192], esb_lo[8192];
    __shared__ float thresh_s[128];

    const int nflag = min(*pcount, MAXFLAG);
    const int st = blockIdx.x >> 3;     // slot tile
    const int kt = blockIdx.x & 7;      // code tile
    const int p0 = st << 7;
    if (p0 >= nflag) return;
    const int tid = threadIdx.x;
    if (tid < 128) {
        const int s = p0 + tid;
        thresh_s[tid] = (s < nflag) ? (m1_arr[plist[s]] + CAND_MARGIN) : -3.0e38f;
    }

    const int lane = tid & 63;
    const int wid  = tid >> 6;
    const int wr = wid >> 1, wc = wid & 1;
    const int l15 = lane & 15, l4 = lane >> 4;

    const char* xhb = (const char*)xgt_hi + ((size_t)st << 16);
    const char* xlb = (const char*)xgt_lo + ((size_t)st << 16);
    const char* ehb = (const char*)et_hi + ((size_t)(kt << 2) << 14);
    const char* elb = (const char*)et_lo + ((size_t)(kt << 2) << 14);

    float4v acc[4][4];
    const float4v zero4 = {0.f, 0.f, 0.f, 0.f};
#pragma unroll
    for (int pf = 0; pf < 4; ++pf)
#pragma unroll
        for (int cf = 0; cf < 4; ++cf) acc[pf][cf] = zero4;

    for (int ct = 0; ct < 4; ++ct) {
        const int coff = ct << 14;
        __syncthreads();
#pragma unroll
        for (int i = 0; i < 4; ++i) {
            const int off = (((i << 2) + wid) << 10);
            const int src = off + (lane << 4);
            __builtin_amdgcn_global_load_lds((gvoid*)(xhb + coff + src),
                (lvoid*)((char*)xsb_hi + off), 16, 0, 0);
            __builtin_amdgcn_global_load_lds((gvoid*)(xlb + coff + src),
                (lvoid*)((char*)xsb_lo + off), 16, 0, 0);
            __builtin_amdgcn_global_load_lds((gvoid*)(ehb + coff + src),
                (lvoid*)((char*)esb_hi + off), 16, 0, 0);
            __builtin_amdgcn_global_load_lds((gvoid*)(elb + coff + src),
                (lvoid*)((char*)esb_lo + off), 16, 0, 0);
        }
        __syncthreads();
#pragma unroll
        for (int ks = 0; ks < 2; ++ks) {
            const int cgb = (ks << 2) + l4;
            const int ebase = (cgb << 7) + (wc << 6) + l15;
            const int xbase = (cgb << 7) + (wr << 6) + l15;
            bf16x8v eh[4], el[4];
#pragma unroll
            for (int cf = 0; cf < 4; ++cf) {
                const int eo = (ebase + (cf << 4)) << 3;
                eh[cf] = *(const bf16x8v*)(esb_hi + eo);
                el[cf] = *(const bf16x8v*)(esb_lo + eo);
            }
#pragma unroll
            for (int pf = 0; pf < 4; ++pf) {
                const int xo = (xbase + (pf << 4)) << 3;
                const bf16x8v xh = *(const bf16x8v*)(xsb_hi + xo);
                const bf16x8v xl = *(const bf16x8v*)(xsb_lo + xo);
#pragma unroll
                for (int cf = 0; cf < 4; ++cf) {
                    acc[pf][cf] = __builtin_amdgcn_mfma_f32_16x16x32_bf16(eh[cf], xh, acc[pf][cf], 0, 0, 0);
                    acc[pf][cf] = __builtin_amdgcn_mfma_f32_16x16x32_bf16(eh[cf], xl, acc[pf][cf], 0, 0, 0);
                    acc[pf][cf] = __builtin_amdgcn_mfma_f32_16x16x32_bf16(el[cf], xh, acc[pf][cf], 0, 0, 0);
                }
            }
        }
    }

    const int k0 = kt << 7;
#pragma unroll
    for (int cf = 0; cf < 4; ++cf) {
        const int kb = k0 + (wc << 6) + (cf << 4) + (l4 << 2);
        const float4v ev = *(const float4v*)(esq + kb);
#pragma unroll
        for (int pf = 0; pf < 4; ++pf) {
            const int slotl = (wr << 6) + (pf << 4) + l15;
            const int slotg = p0 + slotl;
            if (slotg < nflag) {
                const float th = thresh_s[slotl];
#pragma unroll
                for (int r = 0; r < 4; ++r) {
                    const float s = fmaf(-2.0f, acc[pf][cf][r], ev[r]);
                    if (s <= th) {
                        int pos = atomicAdd(ccount, 1);
                        if (pos < MAXCAND) cand[pos] = ((u32)slotg << 10) | (u32)(kb + r);
                    }
                }
            }
        }
    }
}

// ---------------------------------------------------------------------------
// Exact np rescore: one thread per candidate (unchanged).
// ---------------------------------------------------------------------------
__global__ __launch_bounds__(256) void vq_cand_np(const float* __restrict__ xg,
                                                  const float* __restrict__ emb,
                                                  const float* __restrict__ esq,
                                                  const float* __restrict__ xsq_arr,
                                                  const u32* __restrict__ cand,
                                                  const int* __restrict__ ccount,
                                                  u64* __restrict__ best_arr) {
    const int ncand = min(*ccount, MAXCAND);
    const int id = blockIdx.x * 256 + threadIdx.x;
    if (id >= ncand) return;
    const u32 v = cand[id];
    const int slot = (int)(v >> 10);
    const int k = (int)(v & 1023u);
    const float cr = np_einsum_dot_256(xg + (size_t)slot * C_, emb + (size_t)k * C_);
    const float d2 = fadd_x(fsub_x(xsq_arr[slot], fmul_x(2.0f, cr)), esq[k]);
    const u64 pk = ((u64)__float_as_uint(d2) << 32) | (unsigned)k;
    atomicMin(&best_arr[slot], pk);
}

__global__ __launch_bounds__(256) void finalize_kernel(const u64* __restrict__ best_arr,
                                                       const int* __restrict__ plist,
                                                       const int* __restrict__ pcount,
                                                       int* __restrict__ idx_arr) {
    const int nflag = min(*pcount, MAXFLAG);
    const int s = blockIdx.x * 256 + threadIdx.x;
    if (s >= nflag) return;
    idx_arr[plist[s]] = (int)(best_arr[s] & 0xffffffffu);
}

// ---------------------------------------------------------------------------
// gather + STE: out = fl(fl(q - x) + x). Runs LAST. float4-vectorized
// write phase (validated round 16).
// ---------------------------------------------------------------------------
__global__ __launch_bounds__(256) void gather_kernel(const float* __restrict__ x,
                                                     const float* __restrict__ emb,
                                                     const int* __restrict__ idx_arr,
                                                     float* __restrict__ out) {
    __shared__ int idx_s[128];
    __shared__ float qs[32][257];
    const int tid = threadIdx.x;
    const int blk = blockIdx.x;
    const int b   = blk >> 3;
    const int hw0 = (blk & 7) << 7;
    if (tid < 128) idx_s[tid] = idx_arr[blk * 128 + tid];
    __syncthreads();
    for (int ch = 0; ch < 4; ++ch) {
        const int p0c = ch << 5;
#pragma unroll 8
        for (int r = 0; r < 32; ++r)
            qs[r][tid] = emb[(size_t)idx_s[p0c + r] * C_ + tid];
        __syncthreads();
#pragma unroll
        for (int i = 0; i < 8; ++i) {
            const int lin = (i << 8) + tid;     // 0..2047
            const int c = lin >> 3;
            const int px0 = (lin & 7) << 2;
            const size_t o = ((size_t)b * C_ + c) * HW_ + hw0 + p0c + px0;
            const float4 xv = *(const float4*)(x + o);
            float4 ov;
            ov.x = fadd_x(fsub_x(qs[px0 + 0][c], xv.x), xv.x);
            ov.y = fadd_x(fsub_x(qs[px0 + 1][c], xv.y), xv.y);
            ov.z = fadd_x(fsub_x(qs[px0 + 2][c], xv.z), xv.z);
            ov.w = fadd_x(fsub_x(qs[px0 + 3][c], xv.w), xv.w);
            *(float4*)(out + o) = ov;
        }
        __syncthreads();
    }
}

extern "C" void kernel_launch(void* const* d_in, const int* in_sizes, int n_in,
                              void* d_out, int out_size, void* d_ws, size_t ws_size,
                              hipStream_t stream) {
    const float* x   = (const float*)d_in[0];
    const float* emb = (const float*)d_in[1];
    float* out = (float*)d_out;
    char* ws = (char*)d_ws;

    float* esq     = (float*)ws;                 // 4 KB
    int*   pcount  = (int*)(ws + 4096);
    int*   ccount  = (int*)(ws + 8192);
    int*   plist   = (int*)(ws + 12288);         // 32 KB
    float* m1_arr  = (float*)(ws + 65536);       // 256 KB
    int*   idx_arr = (int*)(ws + 327680);        // 256 KB
    float* xsq_arr = (float*)(ws + 589824);      // 32 KB
    u64*   best_arr= (u64*)(ws + 622592);        // 64 KB
    u32*   cand    = (u32*)(ws + 688128);        // 256 KB
    u16*   et_hi   = (u16*)(ws + 983040);        // 512 KB (tiled layout)
    u16*   et_lo   = (u16*)(ws + 1507328);       // 512 KB (base ends ~2 MB)

    // Rescue scratch lives in the out buffer (free until gather runs last).
    float* xg      = (float*)d_out;                           // 8 MB
    u16*   xgt_hi  = (u16*)((char*)d_out + (8u << 20));       // 4 MB
    u16*   xgt_lo  = (u16*)((char*)d_out + (12u << 20));      // 4 MB

    prep_e_kernel<<<K_ / 32, 256, 0, stream>>>(emb, esq, et_hi, et_lo, pcount, ccount);
    vq_main_mfma<<<NPIX / 64, 512, 0, stream>>>(x, et_hi, et_lo, esq,
                                                idx_arr, m1_arr, plist, pcount);
    gather_x_kernel<<<MAXFLAG / 8, 256, 0, stream>>>(x, plist, pcount, xg, xsq_arr,
                                                     best_arr, xgt_hi, xgt_lo);
    vq_scan_mfma<<<(MAXFLAG / 128) * 8, 256, 0, stream>>>(xgt_hi, xgt_lo, et_hi, et_lo,
                                                          esq, m1_arr, plist, pcount,
                                                          cand, ccount);
    vq_cand_np<<<MAXCAND / 256, 256, 0, stream>>>(xg, emb, esq, xsq_arr, cand, ccount,
                                                  best_arr);
    finalize_kernel<<<MAXFLAG / 256, 256, 0, stream>>>(best_arr, plist, pcount, idx_arr);
    gather_kernel<<<NPIX / 128, 256, 0, stream>>>(x, emb, idx_arr, out);
}